// Round 1
// baseline (1662.253 us; speedup 1.0000x reference)
//
#include <hip/hip_runtime.h>
#include <math.h>

#define CCH 256
#define NPOOL 7
#define NCLS 81
#define DCLS 80
#define FLOG_MAX 4.1351666f  /* log(1000/16) */

// ---------------------------------------------------------------------------
// Kernel 1: level assignment + RoI align. grid = R*49 blocks, block = 256 (=C)
// pooled layout: [roi][py][px][c]  (matches reshape(R,-1) feeding W0)
// ---------------------------------------------------------------------------
__global__ void roi_align_k(const float* __restrict__ prop,
                            const int* __restrict__ imidx,
                            const float* __restrict__ f0,
                            const float* __restrict__ f1,
                            const float* __restrict__ f2,
                            const float* __restrict__ f3,
                            int h0, int h1, int h2, int h3,
                            float* __restrict__ pooled)
{
    int b = blockIdx.x;
    int roi = b / 49, p = b % 49;
    int py = p / 7, px = p % 7;

    const float* pr = prop + (size_t)roi * 4;
    float x1 = pr[0], y1 = pr[1], x2 = pr[2], y2 = pr[3];
    float pw = x2 - x1, ph = y2 - y1;

    float lv = floorf(4.0f + log2f(sqrtf(pw * ph) / 224.0f + 1e-6f));
    lv = fminf(fmaxf(lv, 2.0f), 5.0f);
    int lvl = (int)lv - 2;

    const float* fm; int H; float s;
    if (lvl == 0)      { fm = f0; H = h0; s = 0.25f;    }
    else if (lvl == 1) { fm = f1; H = h1; s = 0.125f;   }
    else if (lvl == 2) { fm = f2; H = h2; s = 0.0625f;  }
    else               { fm = f3; H = h3; s = 0.03125f; }
    int W = H;

    float xs1 = x1 * s, ys1 = y1 * s, xs2 = x2 * s, ys2 = y2 * s;
    float gx = (px + 0.5f) / 7.0f, gy = (py + 0.5f) / 7.0f;
    float xx = xs1 + gx * (xs2 - xs1) - 0.5f;
    float yy = ys1 + gy * (ys2 - ys1) - 0.5f;
    float x0f = floorf(xx), y0f = floorf(yy);
    float wx = xx - x0f, wy = yy - y0f;
    int x0i = min(max((int)x0f, 0), W - 1);
    int x1i = min(max((int)x0f + 1, 0), W - 1);
    int y0i = min(max((int)y0f, 0), H - 1);
    int y1i = min(max((int)y0f + 1, 0), H - 1);

    int ii = imidx[roi];
    const float* base = fm + (size_t)ii * H * W * CCH;
    int c = threadIdx.x;
    float v00 = base[((size_t)y0i * W + x0i) * CCH + c];
    float v01 = base[((size_t)y0i * W + x1i) * CCH + c];
    float v10 = base[((size_t)y1i * W + x0i) * CCH + c];
    float v11 = base[((size_t)y1i * W + x1i) * CCH + c];

    float v = v00 * (1.0f - wx) * (1.0f - wy)
            + v01 * wx * (1.0f - wy)
            + v10 * (1.0f - wx) * wy
            + v11 * wx * wy;

    pooled[((size_t)roi * 49 + p) * CCH + c] = v;
}

// ---------------------------------------------------------------------------
// Kernel 2: tiled fp32 GEMM:  Co[M,N] = act(A[M,K] @ B[K,N] + bias)
// BM=BN=64, BK=16, 256 threads, 4x4 micro-tile per thread.
// K must be a multiple of 16 and A 16B-aligned with K%4==0 (true here).
// N may be arbitrary (guarded).
// ---------------------------------------------------------------------------
__global__ __launch_bounds__(256) void gemm_k(const float* __restrict__ A,
                                              const float* __restrict__ B,
                                              const float* __restrict__ bias,
                                              float* __restrict__ Co,
                                              int M, int N, int K, int relu)
{
    __shared__ float Ast[16][68];  // [k][row], padded
    __shared__ float Bs[16][68];   // [k][col], padded

    int m0 = blockIdx.y * 64, n0 = blockIdx.x * 64;
    int tid = threadIdx.x;
    int tx = tid & 15, ty = tid >> 4;

    float acc[4][4] = {};

    for (int k0 = 0; k0 < K; k0 += 16) {
        // A tile: 64 rows x 16 k, float4 per thread
        {
            int row = tid >> 2;
            int kq4 = (tid & 3) * 4;
            const float4 av4 = *(const float4*)(A + (size_t)(m0 + row) * K + k0 + kq4);
            Ast[kq4 + 0][row] = av4.x;
            Ast[kq4 + 1][row] = av4.y;
            Ast[kq4 + 2][row] = av4.z;
            Ast[kq4 + 3][row] = av4.w;
        }
        // B tile: 16 k x 64 cols, guarded scalar loads
        {
            int kr = tid >> 4;
            int cq = (tid & 15) * 4;
            const float* bp = B + (size_t)(k0 + kr) * N + n0 + cq;
#pragma unroll
            for (int e = 0; e < 4; ++e) {
                float v = (n0 + cq + e < N) ? bp[e] : 0.0f;
                Bs[kr][cq + e] = v;
            }
        }
        __syncthreads();

#pragma unroll
        for (int kk = 0; kk < 16; ++kk) {
            float4 af = *(const float4*)&Ast[kk][ty * 4];
            float4 bf = *(const float4*)&Bs[kk][tx * 4];
            float av[4] = {af.x, af.y, af.z, af.w};
            float bv[4] = {bf.x, bf.y, bf.z, bf.w};
#pragma unroll
            for (int i = 0; i < 4; ++i)
#pragma unroll
                for (int j = 0; j < 4; ++j)
                    acc[i][j] = fmaf(av[i], bv[j], acc[i][j]);
        }
        __syncthreads();
    }

#pragma unroll
    for (int i = 0; i < 4; ++i) {
        int row = m0 + ty * 4 + i;
#pragma unroll
        for (int j = 0; j < 4; ++j) {
            int col = n0 + tx * 4 + j;
            if (col < N) {
                float v = acc[i][j] + bias[col];
                if (relu) v = fmaxf(v, 0.0f);
                Co[(size_t)row * N + col] = v;
            }
        }
    }
}

// ---------------------------------------------------------------------------
// Kernel 3: per-row softmax over 81 logits; writes classes 1..80 compactly.
// grid = R blocks, block = 64 (one wave)
// ---------------------------------------------------------------------------
__global__ void softmax_k(const float* __restrict__ logits,
                          float* __restrict__ scr)
{
    int r = blockIdx.x;
    int t = threadIdx.x;
    const float* row = logits + (size_t)r * NCLS;

    float v0 = row[t];                                   // t in 0..63 < 81
    float v1 = (t + 64 < NCLS) ? row[t + 64] : -INFINITY;
    float m = fmaxf(v0, v1);
#pragma unroll
    for (int o = 32; o > 0; o >>= 1) m = fmaxf(m, __shfl_down(m, o));
    m = __shfl(m, 0);

    float e0 = expf(v0 - m);
    float e1 = (t + 64 < NCLS) ? expf(v1 - m) : 0.0f;
    float sum = e0 + e1;
#pragma unroll
    for (int o = 32; o > 0; o >>= 1) sum += __shfl_down(sum, o);
    sum = __shfl(sum, 0);
    float inv = 1.0f / sum;

    if (t >= 1)           scr[(size_t)r * DCLS + (t - 1)]  = e0 * inv;  // classes 1..63
    if (t + 64 < NCLS)    scr[(size_t)r * DCLS + (t + 63)] = e1 * inv;  // classes 64..80
}

// ---------------------------------------------------------------------------
// Kernel 4: box decode + validity. One thread per (roi, class-1) candidate.
// ---------------------------------------------------------------------------
__global__ void decode_k(const float* __restrict__ prop,
                         const int* __restrict__ imidx,
                         const float* __restrict__ reg,
                         const float* __restrict__ scr,
                         const float* __restrict__ imsz,
                         const float* __restrict__ score_thr_p,
                         const float* __restrict__ min_size_p,
                         float* __restrict__ boxes,
                         float* __restrict__ bo,
                         float* __restrict__ area,
                         float* __restrict__ smask,
                         int M)
{
    int j = blockIdx.x * blockDim.x + threadIdx.x;
    if (j >= M) return;
    int r = j / DCLS;
    int d = j - r * DCLS;
    int cls = d + 1;

    const float* pr = prop + (size_t)r * 4;
    float pw = pr[2] - pr[0], ph = pr[3] - pr[1];
    float cx = (pr[0] + pr[2]) * 0.5f, cy = (pr[1] + pr[3]) * 0.5f;

    const float* rg = reg + (size_t)r * (NCLS * 4) + cls * 4;
    float dx = rg[0] * 0.1f;
    float dy = rg[1] * 0.1f;
    float dw = fminf(rg[2] * 0.2f, FLOG_MAX);
    float dh = fminf(rg[3] * 0.2f, FLOG_MAX);

    float ncx = dx * pw + cx;
    float ncy = dy * ph + cy;
    float nw = expf(dw) * pw;
    float nh = expf(dh) * ph;

    int ii = imidx[r];
    float hb = imsz[ii * 2 + 0];
    float wb = imsz[ii * 2 + 1];

    float bx1 = fminf(fmaxf(ncx - nw * 0.5f, 0.0f), wb);
    float bx2 = fminf(fmaxf(ncx + nw * 0.5f, 0.0f), wb);
    float by1 = fminf(fmaxf(ncy - nh * 0.5f, 0.0f), hb);
    float by2 = fminf(fmaxf(ncy + nh * 0.5f, 0.0f), hb);

    float s = scr[j];
    float score_thr = score_thr_p[0];
    float min_size = min_size_p[0];
    bool valid = (s > score_thr) && (bx2 - bx1 >= min_size) && (by2 - by1 >= min_size);

    float immax = fmaxf(fmaxf(imsz[0], imsz[1]), fmaxf(imsz[2], imsz[3]));
    float off = (float)cls * (immax + 2.0f);

    boxes[(size_t)j * 4 + 0] = bx1;
    boxes[(size_t)j * 4 + 1] = by1;
    boxes[(size_t)j * 4 + 2] = bx2;
    boxes[(size_t)j * 4 + 3] = by2;
    bo[(size_t)j * 4 + 0] = bx1 + off;
    bo[(size_t)j * 4 + 1] = by1 + off;
    bo[(size_t)j * 4 + 2] = bx2 + off;
    bo[(size_t)j * 4 + 3] = by2 + off;
    area[j] = (bx2 - bx1) * (by2 - by1);
    smask[j] = valid ? s : -1.0f;
}

// ---------------------------------------------------------------------------
// Kernel 5: per-image NMS. grid = n blocks, block = 1024.
// Compaction (unordered, ties resolved by original index in argmax) then
// imtop sequential iterations of argmax + suppress.
// ---------------------------------------------------------------------------
#define NMS_T 1024
__global__ __launch_bounds__(NMS_T) void nms_k(const float* __restrict__ smask,
                                               const float* __restrict__ bo,
                                               const float* __restrict__ area,
                                               const float* __restrict__ boxes,
                                               const int* __restrict__ imidx,
                                               const float* __restrict__ iou_thr_p,
                                               int* __restrict__ cidx,
                                               float* __restrict__ cscore,
                                               float* __restrict__ cbo,
                                               float* __restrict__ carea,
                                               float* __restrict__ out,
                                               int M, int n, int imtop)
{
    int img = blockIdx.x;
    int t = threadIdx.x;
    const int T = NMS_T;

    __shared__ int cnt;
    __shared__ float rs[NMS_T];
    __shared__ int rg[NMS_T];
    __shared__ int rl[NMS_T];
    __shared__ float wb0, wb1, wb2, wb3, wa;

    if (t == 0) cnt = 0;
    __syncthreads();

    int base = img * M;
    for (int j = t; j < M; j += T) {
        if (imidx[j / DCLS] == img && smask[j] > 0.0f) {
            int p = atomicAdd(&cnt, 1);
            cidx[base + p] = j;
            cscore[base + p] = smask[j];
            cbo[(size_t)(base + p) * 4 + 0] = bo[(size_t)j * 4 + 0];
            cbo[(size_t)(base + p) * 4 + 1] = bo[(size_t)j * 4 + 1];
            cbo[(size_t)(base + p) * 4 + 2] = bo[(size_t)j * 4 + 2];
            cbo[(size_t)(base + p) * 4 + 3] = bo[(size_t)j * 4 + 3];
            carea[base + p] = area[j];
        }
    }
    __syncthreads();
    int K = cnt;
    float iou_thr = iou_thr_p[0];

    float* ob  = out;
    float* osc = out + (size_t)n * imtop * 4;
    float* ocl = out + (size_t)n * imtop * 5;

    int it = 0;
    for (; it < imtop; ++it) {
        // block argmax over compacted list, tie-break by smaller global index
        float best = -1e30f; int bg = 0x7fffffff; int bl = -1;
        for (int p = t; p < K; p += T) {
            float sv = cscore[base + p];
            int g = cidx[base + p];
            if (sv > best || (sv == best && g < bg)) { best = sv; bg = g; bl = p; }
        }
        rs[t] = best; rg[t] = bg; rl[t] = bl;
        __syncthreads();
        for (int o = T / 2; o > 0; o >>= 1) {
            if (t < o) {
                if (rs[t + o] > rs[t] || (rs[t + o] == rs[t] && rg[t + o] < rg[t])) {
                    rs[t] = rs[t + o]; rg[t] = rg[t + o]; rl[t] = rl[t + o];
                }
            }
            __syncthreads();
        }
        float s = rs[0]; int g = rg[0]; int lp = rl[0];
        if (s <= 0.0f) break;

        if (t == 0) {
            size_t oslot = (size_t)img * imtop + it;
            ob[oslot * 4 + 0] = boxes[(size_t)g * 4 + 0];
            ob[oslot * 4 + 1] = boxes[(size_t)g * 4 + 1];
            ob[oslot * 4 + 2] = boxes[(size_t)g * 4 + 2];
            ob[oslot * 4 + 3] = boxes[(size_t)g * 4 + 3];
            osc[oslot] = s;
            ocl[oslot] = (float)(g % DCLS + 1);
            wb0 = cbo[(size_t)(base + lp) * 4 + 0];
            wb1 = cbo[(size_t)(base + lp) * 4 + 1];
            wb2 = cbo[(size_t)(base + lp) * 4 + 2];
            wb3 = cbo[(size_t)(base + lp) * 4 + 3];
            wa  = carea[base + lp];
            cscore[base + lp] = -1.0f;
        }
        __syncthreads();
        float b0 = wb0, b1 = wb1, b2 = wb2, b3 = wb3, ai = wa;
        for (int p = t; p < K; p += T) {
            float c0 = cbo[(size_t)(base + p) * 4 + 0];
            float c1 = cbo[(size_t)(base + p) * 4 + 1];
            float c2 = cbo[(size_t)(base + p) * 4 + 2];
            float c3 = cbo[(size_t)(base + p) * 4 + 3];
            float iw = fmaxf(fminf(b2, c2) - fmaxf(b0, c0), 0.0f);
            float ih = fmaxf(fminf(b3, c3) - fmaxf(b1, c1), 0.0f);
            float inter = iw * ih;
            float iou = inter / (ai + carea[base + p] - inter + 1e-6f);
            if (iou > iou_thr) cscore[base + p] = -1.0f;
        }
        __syncthreads();
    }

    // remaining slots: keep == false -> box 0, score 0, class -1
    for (int q = it + t; q < imtop; q += T) {
        size_t oslot = (size_t)img * imtop + q;
        ob[oslot * 4 + 0] = 0.0f;
        ob[oslot * 4 + 1] = 0.0f;
        ob[oslot * 4 + 2] = 0.0f;
        ob[oslot * 4 + 3] = 0.0f;
        osc[oslot] = 0.0f;
        ocl[oslot] = -1.0f;
    }
}

// ---------------------------------------------------------------------------
extern "C" void kernel_launch(void* const* d_in, const int* in_sizes, int n_in,
                              void* d_out, int out_size, void* d_ws, size_t ws_size,
                              hipStream_t stream)
{
    const float* prop   = (const float*)d_in[0];
    const int*   imidx  = (const int*)d_in[1];
    const float* f0     = (const float*)d_in[2];
    const float* f1     = (const float*)d_in[3];
    const float* f2     = (const float*)d_in[4];
    const float* f3     = (const float*)d_in[5];
    const float* W0     = (const float*)d_in[6];
    const float* b0     = (const float*)d_in[7];
    const float* W1     = (const float*)d_in[8];
    const float* b1     = (const float*)d_in[9];
    const float* Wc     = (const float*)d_in[10];
    const float* bc     = (const float*)d_in[11];
    const float* Wr     = (const float*)d_in[12];
    const float* br     = (const float*)d_in[13];
    const float* imsz   = (const float*)d_in[14];
    const float* sthr   = (const float*)d_in[15];
    const float* ithr   = (const float*)d_in[16];
    const float* msz    = (const float*)d_in[18];

    int R = in_sizes[1];              // 1024
    int n = in_sizes[14] / 2;         // 2
    int imtop = out_size / (n * 6);   // 100
    int M = R * DCLS;                 // 81920
    int K0 = NPOOL * NPOOL * CCH;     // 12544
    int CL = in_sizes[7];             // 1024 (b0 size)

    // fmap spatial dims from sizes: size = n * h * h * C
    int h0 = (int)(sqrtf((float)(in_sizes[2] / (n * CCH))) + 0.5f);
    int h1 = (int)(sqrtf((float)(in_sizes[3] / (n * CCH))) + 0.5f);
    int h2 = (int)(sqrtf((float)(in_sizes[4] / (n * CCH))) + 0.5f);
    int h3 = (int)(sqrtf((float)(in_sizes[5] / (n * CCH))) + 0.5f);

    float* ws = (float*)d_ws;
    size_t off = 0;
    float* pooled = ws + off; off += (size_t)R * K0;       // 12,845,056
    float* x0     = ws + off; off += (size_t)R * CL;       // 1,048,576
    float* x1     = ws + off; off += (size_t)R * CL;
    float* logits = ws + off; off += (size_t)R * NCLS;     // 82,944
    off = (off + 3) & ~(size_t)3;
    float* reg    = ws + off; off += (size_t)R * NCLS * 4; // 331,776
    float* scr    = ws + off; off += (size_t)R * DCLS;     // 81,920

    // decode/NMS arrays alias the pooled region (pooled dead by then)
    float* boxes = ws;
    float* bo    = boxes + (size_t)M * 4;
    float* area  = bo + (size_t)M * 4;
    float* smask = area + M;
    int*   cidx  = (int*)(smask + M);
    float* cscore = (float*)(cidx + (size_t)n * M);
    float* cbo   = cscore + (size_t)n * M;
    float* carea = cbo + (size_t)n * M * 4;

    float* outf = (float*)d_out;

    // 1. RoI align
    roi_align_k<<<dim3(R * 49), dim3(256), 0, stream>>>(
        prop, imidx, f0, f1, f2, f3, h0, h1, h2, h3, pooled);

    // 2. FC0: x0 = relu(pooled @ W0 + b0)   [R x 12544] @ [12544 x 1024]
    gemm_k<<<dim3(CL / 64, R / 64), dim3(256), 0, stream>>>(
        pooled, W0, b0, x0, R, CL, K0, 1);

    // 3. FC1: x1 = relu(x0 @ W1 + b1)
    gemm_k<<<dim3(CL / 64, R / 64), dim3(256), 0, stream>>>(
        x0, W1, b1, x1, R, CL, CL, 1);

    // 4. heads
    gemm_k<<<dim3((NCLS + 63) / 64, R / 64), dim3(256), 0, stream>>>(
        x1, Wc, bc, logits, R, NCLS, CL, 0);
    gemm_k<<<dim3((NCLS * 4 + 63) / 64, R / 64), dim3(256), 0, stream>>>(
        x1, Wr, br, reg, R, NCLS * 4, CL, 0);

    // 5. softmax + decode
    softmax_k<<<dim3(R), dim3(64), 0, stream>>>(logits, scr);
    decode_k<<<dim3((M + 255) / 256), dim3(256), 0, stream>>>(
        prop, imidx, reg, scr, imsz, sthr, msz,
        boxes, bo, area, smask, M);

    // 6. NMS + output
    nms_k<<<dim3(n), dim3(NMS_T), 0, stream>>>(
        smask, bo, area, boxes, imidx, ithr,
        cidx, cscore, cbo, carea, outf, M, n, imtop);
}

// Round 2
// 773.664 us; speedup vs baseline: 2.1485x; 2.1485x over previous
//
#include <hip/hip_runtime.h>
#include <math.h>

#define CCH 256
#define NPOOL 7
#define NCLS 81
#define DCLS 80
#define FLOG_MAX 4.1351666f  /* log(1000/16) */

// ---------------------------------------------------------------------------
// Kernel 0: zero a float region (float4 stores). count4 = #float4 elements.
// ---------------------------------------------------------------------------
__global__ void zero_k(float4* __restrict__ p, int count4)
{
    int i = blockIdx.x * blockDim.x + threadIdx.x;
    if (i < count4) p[i] = make_float4(0.f, 0.f, 0.f, 0.f);
}

// ---------------------------------------------------------------------------
// Kernel 1: level assignment + RoI align. grid = R*49 blocks, block = 256 (=C)
// pooled layout: [roi][py][px][c]
// ---------------------------------------------------------------------------
__global__ void roi_align_k(const float* __restrict__ prop,
                            const int* __restrict__ imidx,
                            const float* __restrict__ f0,
                            const float* __restrict__ f1,
                            const float* __restrict__ f2,
                            const float* __restrict__ f3,
                            int h0, int h1, int h2, int h3,
                            float* __restrict__ pooled)
{
    int b = blockIdx.x;
    int roi = b / 49, p = b % 49;
    int py = p / 7, px = p % 7;

    const float* pr = prop + (size_t)roi * 4;
    float x1 = pr[0], y1 = pr[1], x2 = pr[2], y2 = pr[3];
    float pw = x2 - x1, ph = y2 - y1;

    float lv = floorf(4.0f + log2f(sqrtf(pw * ph) / 224.0f + 1e-6f));
    lv = fminf(fmaxf(lv, 2.0f), 5.0f);
    int lvl = (int)lv - 2;

    const float* fm; int H; float s;
    if (lvl == 0)      { fm = f0; H = h0; s = 0.25f;    }
    else if (lvl == 1) { fm = f1; H = h1; s = 0.125f;   }
    else if (lvl == 2) { fm = f2; H = h2; s = 0.0625f;  }
    else               { fm = f3; H = h3; s = 0.03125f; }
    int W = H;

    float xs1 = x1 * s, ys1 = y1 * s, xs2 = x2 * s, ys2 = y2 * s;
    float gx = (px + 0.5f) / 7.0f, gy = (py + 0.5f) / 7.0f;
    float xx = xs1 + gx * (xs2 - xs1) - 0.5f;
    float yy = ys1 + gy * (ys2 - ys1) - 0.5f;
    float x0f = floorf(xx), y0f = floorf(yy);
    float wx = xx - x0f, wy = yy - y0f;
    int x0i = min(max((int)x0f, 0), W - 1);
    int x1i = min(max((int)x0f + 1, 0), W - 1);
    int y0i = min(max((int)y0f, 0), H - 1);
    int y1i = min(max((int)y0f + 1, 0), H - 1);

    int ii = imidx[roi];
    const float* base = fm + (size_t)ii * H * W * CCH;
    int c = threadIdx.x;
    float v00 = base[((size_t)y0i * W + x0i) * CCH + c];
    float v01 = base[((size_t)y0i * W + x1i) * CCH + c];
    float v10 = base[((size_t)y1i * W + x0i) * CCH + c];
    float v11 = base[((size_t)y1i * W + x1i) * CCH + c];

    float v = v00 * (1.0f - wx) * (1.0f - wy)
            + v01 * wx * (1.0f - wy)
            + v10 * (1.0f - wx) * wy
            + v11 * wx * wy;

    pooled[((size_t)roi * 49 + p) * CCH + c] = v;
}

// ---------------------------------------------------------------------------
// Kernel 2: split-K tiled fp32 GEMM with optional fused A-side bias+ReLU:
//   Cacc[M,N] += (relu(A + abias[k]) if abias else A)[M,K] @ B[K,N]
// BM=BN=64, BK=16, 256 threads, 4x4 micro-tile. grid = (ceil(N/64), M/64, S).
// Kc = K-span per z-slice (multiple of 16). Cacc must be pre-zeroed.
// M%64==0, K%16==0 required (true here). N arbitrary (guarded).
// ---------------------------------------------------------------------------
__global__ __launch_bounds__(256) void gemm_splitk_k(const float* __restrict__ A,
                                                     const float* __restrict__ B,
                                                     const float* __restrict__ abias,
                                                     float* __restrict__ Cacc,
                                                     int M, int N, int K, int Kc)
{
    __shared__ float Ast[16][68];  // [k][row], 2-way max (free)
    __shared__ float Bs[16][68];   // [k][col], 2-way max (free)

    int m0 = blockIdx.y * 64, n0 = blockIdx.x * 64;
    int kb = blockIdx.z * Kc;
    int ke = min(K, kb + Kc);
    int tid = threadIdx.x;
    int tx = tid & 15, ty = tid >> 4;
    int arow = tid >> 2, akq = (tid & 3) << 2;   // A loader: row, k-quad
    int bcol = tid & 63, bk = tid >> 6;          // B loader: 64 lanes = 64 cols

    const float* Arow = A + (size_t)(m0 + arow) * K;
    bool nfull = (n0 + 64 <= N);

    float acc[4][4] = {};

    for (int k0 = kb; k0 < ke; k0 += 16) {
        float4 av = *(const float4*)(Arow + k0 + akq);
        if (abias) {
            av.x = fmaxf(av.x + abias[k0 + akq + 0], 0.0f);
            av.y = fmaxf(av.y + abias[k0 + akq + 1], 0.0f);
            av.z = fmaxf(av.z + abias[k0 + akq + 2], 0.0f);
            av.w = fmaxf(av.w + abias[k0 + akq + 3], 0.0f);
        }
        float bv[4];
        if (nfull) {
#pragma unroll
            for (int e = 0; e < 4; ++e)
                bv[e] = B[(size_t)(k0 + bk * 4 + e) * N + n0 + bcol];
        } else {
            bool ok = (n0 + bcol) < N;
#pragma unroll
            for (int e = 0; e < 4; ++e)
                bv[e] = ok ? B[(size_t)(k0 + bk * 4 + e) * N + n0 + bcol] : 0.0f;
        }
        __syncthreads();   // previous iteration's reads complete
        Ast[akq + 0][arow] = av.x;
        Ast[akq + 1][arow] = av.y;
        Ast[akq + 2][arow] = av.z;
        Ast[akq + 3][arow] = av.w;
#pragma unroll
        for (int e = 0; e < 4; ++e) Bs[bk * 4 + e][bcol] = bv[e];
        __syncthreads();

#pragma unroll
        for (int kk = 0; kk < 16; ++kk) {
            float4 af = *(const float4*)&Ast[kk][ty * 4];
            float4 bf = *(const float4*)&Bs[kk][tx * 4];
            float a_[4] = {af.x, af.y, af.z, af.w};
            float b_[4] = {bf.x, bf.y, bf.z, bf.w};
#pragma unroll
            for (int i = 0; i < 4; ++i)
#pragma unroll
                for (int j = 0; j < 4; ++j)
                    acc[i][j] = fmaf(a_[i], b_[j], acc[i][j]);
        }
    }

#pragma unroll
    for (int i = 0; i < 4; ++i) {
        int row = m0 + ty * 4 + i;
#pragma unroll
        for (int j = 0; j < 4; ++j) {
            int col = n0 + tx * 4 + j;
            if (col < N) atomicAdd(&Cacc[(size_t)row * N + col], acc[i][j]);
        }
    }
}

// ---------------------------------------------------------------------------
// Kernel 3: per-row softmax over (logits + bc); writes classes 1..80.
// grid = R blocks, block = 64 (one wave)
// ---------------------------------------------------------------------------
__global__ void softmax_k(const float* __restrict__ logits,
                          const float* __restrict__ bc,
                          float* __restrict__ scr)
{
    int r = blockIdx.x;
    int t = threadIdx.x;
    const float* row = logits + (size_t)r * NCLS;

    float v0 = row[t] + bc[t];
    float v1 = (t + 64 < NCLS) ? (row[t + 64] + bc[t + 64]) : -INFINITY;
    float m = fmaxf(v0, v1);
#pragma unroll
    for (int o = 32; o > 0; o >>= 1) m = fmaxf(m, __shfl_down(m, o));
    m = __shfl(m, 0);

    float e0 = expf(v0 - m);
    float e1 = (t + 64 < NCLS) ? expf(v1 - m) : 0.0f;
    float sum = e0 + e1;
#pragma unroll
    for (int o = 32; o > 0; o >>= 1) sum += __shfl_down(sum, o);
    sum = __shfl(sum, 0);
    float inv = 1.0f / sum;

    if (t >= 1)        scr[(size_t)r * DCLS + (t - 1)]  = e0 * inv;
    if (t + 64 < NCLS) scr[(size_t)r * DCLS + (t + 63)] = e1 * inv;
}

// ---------------------------------------------------------------------------
// Kernel 4: box decode + validity (reg bias br fused here).
// ---------------------------------------------------------------------------
__global__ void decode_k(const float* __restrict__ prop,
                         const int* __restrict__ imidx,
                         const float* __restrict__ reg,
                         const float* __restrict__ br,
                         const float* __restrict__ scr,
                         const float* __restrict__ imsz,
                         const float* __restrict__ score_thr_p,
                         const float* __restrict__ min_size_p,
                         float* __restrict__ boxes,
                         float* __restrict__ bo,
                         float* __restrict__ area,
                         float* __restrict__ smask,
                         int M)
{
    int j = blockIdx.x * blockDim.x + threadIdx.x;
    if (j >= M) return;
    int r = j / DCLS;
    int d = j - r * DCLS;
    int cls = d + 1;

    const float* pr = prop + (size_t)r * 4;
    float pw = pr[2] - pr[0], ph = pr[3] - pr[1];
    float cx = (pr[0] + pr[2]) * 0.5f, cy = (pr[1] + pr[3]) * 0.5f;

    const float* rg = reg + (size_t)r * (NCLS * 4) + cls * 4;
    const float* bb = br + cls * 4;
    float dx = (rg[0] + bb[0]) * 0.1f;
    float dy = (rg[1] + bb[1]) * 0.1f;
    float dw = fminf((rg[2] + bb[2]) * 0.2f, FLOG_MAX);
    float dh = fminf((rg[3] + bb[3]) * 0.2f, FLOG_MAX);

    float ncx = dx * pw + cx;
    float ncy = dy * ph + cy;
    float nw = expf(dw) * pw;
    float nh = expf(dh) * ph;

    int ii = imidx[r];
    float hb = imsz[ii * 2 + 0];
    float wb = imsz[ii * 2 + 1];

    float bx1 = fminf(fmaxf(ncx - nw * 0.5f, 0.0f), wb);
    float bx2 = fminf(fmaxf(ncx + nw * 0.5f, 0.0f), wb);
    float by1 = fminf(fmaxf(ncy - nh * 0.5f, 0.0f), hb);
    float by2 = fminf(fmaxf(ncy + nh * 0.5f, 0.0f), hb);

    float s = scr[j];
    float score_thr = score_thr_p[0];
    float min_size = min_size_p[0];
    bool valid = (s > score_thr) && (bx2 - bx1 >= min_size) && (by2 - by1 >= min_size);

    float immax = fmaxf(fmaxf(imsz[0], imsz[1]), fmaxf(imsz[2], imsz[3]));
    float off = (float)cls * (immax + 2.0f);

    boxes[(size_t)j * 4 + 0] = bx1;
    boxes[(size_t)j * 4 + 1] = by1;
    boxes[(size_t)j * 4 + 2] = bx2;
    boxes[(size_t)j * 4 + 3] = by2;
    bo[(size_t)j * 4 + 0] = bx1 + off;
    bo[(size_t)j * 4 + 1] = by1 + off;
    bo[(size_t)j * 4 + 2] = bx2 + off;
    bo[(size_t)j * 4 + 3] = by2 + off;
    area[j] = (bx2 - bx1) * (by2 - by1);
    smask[j] = valid ? s : -1.0f;
}

// ---------------------------------------------------------------------------
// Kernel 5: per-image NMS. grid = n blocks, block = 1024.
// ---------------------------------------------------------------------------
#define NMS_T 1024
__global__ __launch_bounds__(NMS_T) void nms_k(const float* __restrict__ smask,
                                               const float* __restrict__ bo,
                                               const float* __restrict__ area,
                                               const float* __restrict__ boxes,
                                               const int* __restrict__ imidx,
                                               const float* __restrict__ iou_thr_p,
                                               int* __restrict__ cidx,
                                               float* __restrict__ cscore,
                                               float* __restrict__ cbo,
                                               float* __restrict__ carea,
                                               float* __restrict__ out,
                                               int M, int n, int imtop)
{
    int img = blockIdx.x;
    int t = threadIdx.x;
    const int T = NMS_T;

    __shared__ int cnt;
    __shared__ float rs[NMS_T];
    __shared__ int rg[NMS_T];
    __shared__ int rl[NMS_T];
    __shared__ float wb0, wb1, wb2, wb3, wa;

    if (t == 0) cnt = 0;
    __syncthreads();

    int base = img * M;
    for (int j = t; j < M; j += T) {
        if (imidx[j / DCLS] == img && smask[j] > 0.0f) {
            int p = atomicAdd(&cnt, 1);
            cidx[base + p] = j;
            cscore[base + p] = smask[j];
            cbo[(size_t)(base + p) * 4 + 0] = bo[(size_t)j * 4 + 0];
            cbo[(size_t)(base + p) * 4 + 1] = bo[(size_t)j * 4 + 1];
            cbo[(size_t)(base + p) * 4 + 2] = bo[(size_t)j * 4 + 2];
            cbo[(size_t)(base + p) * 4 + 3] = bo[(size_t)j * 4 + 3];
            carea[base + p] = area[j];
        }
    }
    __syncthreads();
    int K = cnt;
    float iou_thr = iou_thr_p[0];

    float* ob  = out;
    float* osc = out + (size_t)n * imtop * 4;
    float* ocl = out + (size_t)n * imtop * 5;

    int it = 0;
    for (; it < imtop; ++it) {
        float best = -1e30f; int bg = 0x7fffffff; int bl = -1;
        for (int p = t; p < K; p += T) {
            float sv = cscore[base + p];
            int g = cidx[base + p];
            if (sv > best || (sv == best && g < bg)) { best = sv; bg = g; bl = p; }
        }
        rs[t] = best; rg[t] = bg; rl[t] = bl;
        __syncthreads();
        for (int o = T / 2; o > 0; o >>= 1) {
            if (t < o) {
                if (rs[t + o] > rs[t] || (rs[t + o] == rs[t] && rg[t + o] < rg[t])) {
                    rs[t] = rs[t + o]; rg[t] = rg[t + o]; rl[t] = rl[t + o];
                }
            }
            __syncthreads();
        }
        float s = rs[0]; int g = rg[0]; int lp = rl[0];
        if (s <= 0.0f) break;

        if (t == 0) {
            size_t oslot = (size_t)img * imtop + it;
            ob[oslot * 4 + 0] = boxes[(size_t)g * 4 + 0];
            ob[oslot * 4 + 1] = boxes[(size_t)g * 4 + 1];
            ob[oslot * 4 + 2] = boxes[(size_t)g * 4 + 2];
            ob[oslot * 4 + 3] = boxes[(size_t)g * 4 + 3];
            osc[oslot] = s;
            ocl[oslot] = (float)(g % DCLS + 1);
            wb0 = cbo[(size_t)(base + lp) * 4 + 0];
            wb1 = cbo[(size_t)(base + lp) * 4 + 1];
            wb2 = cbo[(size_t)(base + lp) * 4 + 2];
            wb3 = cbo[(size_t)(base + lp) * 4 + 3];
            wa  = carea[base + lp];
            cscore[base + lp] = -1.0f;
        }
        __syncthreads();
        float b0 = wb0, b1 = wb1, b2 = wb2, b3 = wb3, ai = wa;
        for (int p = t; p < K; p += T) {
            float c0 = cbo[(size_t)(base + p) * 4 + 0];
            float c1 = cbo[(size_t)(base + p) * 4 + 1];
            float c2 = cbo[(size_t)(base + p) * 4 + 2];
            float c3 = cbo[(size_t)(base + p) * 4 + 3];
            float iw = fmaxf(fminf(b2, c2) - fmaxf(b0, c0), 0.0f);
            float ih = fmaxf(fminf(b3, c3) - fmaxf(b1, c1), 0.0f);
            float inter = iw * ih;
            float iou = inter / (ai + carea[base + p] - inter + 1e-6f);
            if (iou > iou_thr) cscore[base + p] = -1.0f;
        }
        __syncthreads();
    }

    for (int q = it + t; q < imtop; q += T) {
        size_t oslot = (size_t)img * imtop + q;
        ob[oslot * 4 + 0] = 0.0f;
        ob[oslot * 4 + 1] = 0.0f;
        ob[oslot * 4 + 2] = 0.0f;
        ob[oslot * 4 + 3] = 0.0f;
        osc[oslot] = 0.0f;
        ocl[oslot] = -1.0f;
    }
}

// ---------------------------------------------------------------------------
extern "C" void kernel_launch(void* const* d_in, const int* in_sizes, int n_in,
                              void* d_out, int out_size, void* d_ws, size_t ws_size,
                              hipStream_t stream)
{
    const float* prop   = (const float*)d_in[0];
    const int*   imidx  = (const int*)d_in[1];
    const float* f0     = (const float*)d_in[2];
    const float* f1     = (const float*)d_in[3];
    const float* f2     = (const float*)d_in[4];
    const float* f3     = (const float*)d_in[5];
    const float* W0     = (const float*)d_in[6];
    const float* b0     = (const float*)d_in[7];
    const float* W1     = (const float*)d_in[8];
    const float* b1     = (const float*)d_in[9];
    const float* Wc     = (const float*)d_in[10];
    const float* bc     = (const float*)d_in[11];
    const float* Wr     = (const float*)d_in[12];
    const float* br     = (const float*)d_in[13];
    const float* imsz   = (const float*)d_in[14];
    const float* sthr   = (const float*)d_in[15];
    const float* ithr   = (const float*)d_in[16];
    const float* msz    = (const float*)d_in[18];

    int R = in_sizes[1];              // 1024
    int n = in_sizes[14] / 2;         // 2
    int imtop = out_size / (n * 6);   // 100
    int M = R * DCLS;                 // 81920
    int K0 = NPOOL * NPOOL * CCH;     // 12544
    int CL = in_sizes[7];             // 1024

    int h0 = (int)(sqrtf((float)(in_sizes[2] / (n * CCH))) + 0.5f);
    int h1 = (int)(sqrtf((float)(in_sizes[3] / (n * CCH))) + 0.5f);
    int h2 = (int)(sqrtf((float)(in_sizes[4] / (n * CCH))) + 0.5f);
    int h3 = (int)(sqrtf((float)(in_sizes[5] / (n * CCH))) + 0.5f);

    float* ws = (float*)d_ws;
    size_t off = 0;
    float* pooled  = ws + off; off += (size_t)R * K0;        // 12.8M floats
    float* x0acc   = ws + off; off += (size_t)R * CL;        // raw accum (no bias/relu)
    float* x1acc   = ws + off; off += (size_t)R * CL;
    float* logits  = ws + off; off += (size_t)R * NCLS;      // raw accum (bc fused in softmax)
    off = (off + 3) & ~(size_t)3;
    float* reg     = ws + off; off += (size_t)R * NCLS * 4;  // raw accum (br fused in decode)
    float* scr     = ws + off; off += (size_t)R * DCLS;

    // decode/NMS arrays alias pooled (dead by then)
    float* boxes = ws;
    float* bo    = boxes + (size_t)M * 4;
    float* area  = bo + (size_t)M * 4;
    float* smask = area + M;
    int*   cidx  = (int*)(smask + M);
    float* cscore = (float*)(cidx + (size_t)n * M);
    float* cbo   = cscore + (size_t)n * M;
    float* carea = cbo + (size_t)n * M * 4;

    float* outf = (float*)d_out;

    // 0. zero the atomic-accumulated GEMM outputs (x0acc..reg, contiguous)
    {
        size_t zcount = (size_t)(reg + (size_t)R * NCLS * 4 - x0acc);
        int c4 = (int)(zcount / 4);
        zero_k<<<dim3((c4 + 255) / 256), dim3(256), 0, stream>>>((float4*)x0acc, c4);
    }

    // 1. RoI align
    roi_align_k<<<dim3(R * 49), dim3(256), 0, stream>>>(
        prop, imidx, f0, f1, f2, f3, h0, h1, h2, h3, pooled);

    // 2. FC0: x0acc = pooled @ W0      (split-K 8 -> 2048 blocks)
    gemm_splitk_k<<<dim3(CL / 64, R / 64, 8), dim3(256), 0, stream>>>(
        pooled, W0, nullptr, x0acc, R, CL, K0, 1568);

    // 3. FC1: x1acc = relu(x0acc + b0) @ W1   (split-K 4)
    gemm_splitk_k<<<dim3(CL / 64, R / 64, 4), dim3(256), 0, stream>>>(
        x0acc, W1, b0, x1acc, R, CL, CL, 256);

    // 4. heads: logits = relu(x1acc + b1) @ Wc ; reg = relu(x1acc + b1) @ Wr
    gemm_splitk_k<<<dim3((NCLS + 63) / 64, R / 64, 8), dim3(256), 0, stream>>>(
        x1acc, Wc, b1, logits, R, NCLS, CL, 128);
    gemm_splitk_k<<<dim3((NCLS * 4 + 63) / 64, R / 64, 4), dim3(256), 0, stream>>>(
        x1acc, Wr, b1, reg, R, NCLS * 4, CL, 256);

    // 5. softmax (+bc) + decode (+br)
    softmax_k<<<dim3(R), dim3(64), 0, stream>>>(logits, bc, scr);
    decode_k<<<dim3((M + 255) / 256), dim3(256), 0, stream>>>(
        prop, imidx, reg, br, scr, imsz, sthr, msz,
        boxes, bo, area, smask, M);

    // 6. NMS + output
    nms_k<<<dim3(n), dim3(NMS_T), 0, stream>>>(
        smask, bo, area, boxes, imidx, ithr,
        cidx, cscore, cbo, carea, outf, M, n, imtop);
}

// Round 3
// 547.919 us; speedup vs baseline: 3.0338x; 1.4120x over previous
//
#include <hip/hip_runtime.h>
#include <math.h>

#define CCH 256
#define NPOOL 7
#define NCLS 81
#define DCLS 80
#define FLOG_MAX 4.1351666f  /* log(1000/16) */

typedef _Float16 half8 __attribute__((ext_vector_type(8)));
typedef _Float16 half4 __attribute__((ext_vector_type(4)));
typedef float floatx4 __attribute__((ext_vector_type(4)));

// ---------------------------------------------------------------------------
// Kernel 0: zero a float region (float4 stores).
// ---------------------------------------------------------------------------
__global__ void zero_k(float4* __restrict__ p, int count4)
{
    int i = blockIdx.x * blockDim.x + threadIdx.x;
    if (i < count4) p[i] = make_float4(0.f, 0.f, 0.f, 0.f);
}

// ---------------------------------------------------------------------------
// RoI align core (shared by fp32 and f16-split variants)
// ---------------------------------------------------------------------------
__device__ __forceinline__ float roi_align_val(
    const float* __restrict__ prop, const int* __restrict__ imidx,
    const float* __restrict__ f0, const float* __restrict__ f1,
    const float* __restrict__ f2, const float* __restrict__ f3,
    int h0, int h1, int h2, int h3, int b, int c)
{
    int roi = b / 49, p = b % 49;
    int py = p / 7, px = p % 7;

    const float* pr = prop + (size_t)roi * 4;
    float x1 = pr[0], y1 = pr[1], x2 = pr[2], y2 = pr[3];
    float pw = x2 - x1, ph = y2 - y1;

    float lv = floorf(4.0f + log2f(sqrtf(pw * ph) / 224.0f + 1e-6f));
    lv = fminf(fmaxf(lv, 2.0f), 5.0f);
    int lvl = (int)lv - 2;

    const float* fm; int H; float s;
    if (lvl == 0)      { fm = f0; H = h0; s = 0.25f;    }
    else if (lvl == 1) { fm = f1; H = h1; s = 0.125f;   }
    else if (lvl == 2) { fm = f2; H = h2; s = 0.0625f;  }
    else               { fm = f3; H = h3; s = 0.03125f; }
    int W = H;

    float xs1 = x1 * s, ys1 = y1 * s, xs2 = x2 * s, ys2 = y2 * s;
    float gx = (px + 0.5f) / 7.0f, gy = (py + 0.5f) / 7.0f;
    float xx = xs1 + gx * (xs2 - xs1) - 0.5f;
    float yy = ys1 + gy * (ys2 - ys1) - 0.5f;
    float x0f = floorf(xx), y0f = floorf(yy);
    float wx = xx - x0f, wy = yy - y0f;
    int x0i = min(max((int)x0f, 0), W - 1);
    int x1i = min(max((int)x0f + 1, 0), W - 1);
    int y0i = min(max((int)y0f, 0), H - 1);
    int y1i = min(max((int)y0f + 1, 0), H - 1);

    int ii = imidx[roi];
    const float* base = fm + (size_t)ii * H * W * CCH;
    float v00 = base[((size_t)y0i * W + x0i) * CCH + c];
    float v01 = base[((size_t)y0i * W + x1i) * CCH + c];
    float v10 = base[((size_t)y1i * W + x0i) * CCH + c];
    float v11 = base[((size_t)y1i * W + x1i) * CCH + c];

    return v00 * (1.0f - wx) * (1.0f - wy)
         + v01 * wx * (1.0f - wy)
         + v10 * (1.0f - wx) * wy
         + v11 * wx * wy;
}

// fp32 variant (fallback path)
__global__ void roi_align_k(const float* __restrict__ prop,
                            const int* __restrict__ imidx,
                            const float* __restrict__ f0,
                            const float* __restrict__ f1,
                            const float* __restrict__ f2,
                            const float* __restrict__ f3,
                            int h0, int h1, int h2, int h3,
                            float* __restrict__ pooled)
{
    int b = blockIdx.x, c = threadIdx.x;
    float v = roi_align_val(prop, imidx, f0, f1, f2, f3, h0, h1, h2, h3, b, c);
    pooled[(size_t)b * CCH + c] = v;
}

// f16 hi/lo split variant (MFMA path)
__global__ void roi_align_f16_k(const float* __restrict__ prop,
                                const int* __restrict__ imidx,
                                const float* __restrict__ f0,
                                const float* __restrict__ f1,
                                const float* __restrict__ f2,
                                const float* __restrict__ f3,
                                int h0, int h1, int h2, int h3,
                                _Float16* __restrict__ poolH,
                                _Float16* __restrict__ poolL)
{
    int b = blockIdx.x, c = threadIdx.x;
    float v = roi_align_val(prop, imidx, f0, f1, f2, f3, h0, h1, h2, h3, b, c);
    _Float16 h = (_Float16)v;
    size_t idx = (size_t)b * CCH + c;
    poolH[idx] = h;
    poolL[idx] = (_Float16)(v - (float)h);
}

// ---------------------------------------------------------------------------
// Transpose-convert: W [K][N] fp32  ->  WtH/WtL [N][K] f16 hi/lo.
// grid = (K/64, N/64), block = 256. K%64==0, N%64==0 required.
// ---------------------------------------------------------------------------
__global__ __launch_bounds__(256) void convert_w_t_k(const float* __restrict__ W,
                                                     _Float16* __restrict__ WtH,
                                                     _Float16* __restrict__ WtL,
                                                     int K, int N)
{
    __shared__ float sh[64][65];
    int k0 = blockIdx.x * 64, n0 = blockIdx.y * 64;
    int t = threadIdx.x;
#pragma unroll
    for (int p = 0; p < 4; ++p) {
        int idx = p * 256 + t;
        int kr = idx >> 4, nc = (idx & 15) * 4;
        float4 v = *(const float4*)(W + (size_t)(k0 + kr) * N + n0 + nc);
        sh[kr][nc + 0] = v.x; sh[kr][nc + 1] = v.y;
        sh[kr][nc + 2] = v.z; sh[kr][nc + 3] = v.w;
    }
    __syncthreads();
#pragma unroll
    for (int p = 0; p < 4; ++p) {
        int idx = p * 256 + t;
        int nr = idx >> 4, kc = (idx & 15) * 4;
        half4 h, l;
#pragma unroll
        for (int i = 0; i < 4; ++i) {
            float v = sh[kc + i][nr];
            _Float16 hh = (_Float16)v;
            h[i] = hh;
            l[i] = (_Float16)(v - (float)hh);
        }
        *(half4*)(WtH + (size_t)(n0 + nr) * K + k0 + kc) = h;
        *(half4*)(WtL + (size_t)(n0 + nr) * K + k0 + kc) = l;
    }
}

// ---------------------------------------------------------------------------
// Split-f16 MFMA GEMM (FC0): Cacc[M,N] += A[M,K] @ B[K,N] where
// A = Ah+Al (row-major [M][K]), B given transposed Bt = Bh/Bl [N][K].
// 3 products: ah*bh + ah*bl + al*bh. 128x128 block tile, BK=32, 256 thr
// (4 waves, each 64x64 = 4x4 of 16x16x32 f16 MFMA). Split-K via blockIdx.z,
// fp32 atomicAdd epilogue (Cacc pre-zeroed). M%128==0, N%128==0, Kc%32==0.
// ---------------------------------------------------------------------------
#define LDK 36  // padded k-stride in LDS (f16 elems): 72B -> 2-way banks (free)
__global__ __launch_bounds__(256) void gemm_mfma_split_k(
    const _Float16* __restrict__ Ah, const _Float16* __restrict__ Al,
    const _Float16* __restrict__ Bh, const _Float16* __restrict__ Bl,
    float* __restrict__ Cacc, int M, int N, int K, int Kc)
{
    __shared__ _Float16 sAh[128 * LDK], sAl[128 * LDK];
    __shared__ _Float16 sBh[128 * LDK], sBl[128 * LDK];

    int m0 = blockIdx.y * 128, n0 = blockIdx.x * 128;
    int kb = blockIdx.z * Kc;
    int ke = min(K, kb + Kc);
    int t = threadIdx.x;
    int lane = t & 63, w = t >> 6;
    int wr = w >> 1, wc = w & 1;          // 2x2 wave grid over the 128x128 tile
    int srow = t >> 2, skq = (t & 3) * 8; // staging: 4 threads x 16B per row
    int fr = lane & 15;                   // fragment row/col within 16
    int fk = (lane >> 4) * 8;             // fragment k offset (quad*8)

    floatx4 acc[4][4] = {};

    for (int k0 = kb; k0 < ke; k0 += 32) {
#pragma unroll
        for (int p = 0; p < 2; ++p) {
            int row = srow + p * 64;
            size_t ga = (size_t)(m0 + row) * K + k0 + skq;
            size_t gb = (size_t)(n0 + row) * K + k0 + skq;
            half8 vah = *(const half8*)(Ah + ga);
            half8 val = *(const half8*)(Al + ga);
            half8 vbh = *(const half8*)(Bh + gb);
            half8 vbl = *(const half8*)(Bl + gb);
            *(half8*)&sAh[row * LDK + skq] = vah;
            *(half8*)&sAl[row * LDK + skq] = val;
            *(half8*)&sBh[row * LDK + skq] = vbh;
            *(half8*)&sBl[row * LDK + skq] = vbl;
        }
        __syncthreads();

        half8 ah[4], al[4], bh[4], bl[4];
#pragma unroll
        for (int i = 0; i < 4; ++i) {
            int ar = wr * 64 + i * 16 + fr;
            ah[i] = *(const half8*)&sAh[ar * LDK + fk];
            al[i] = *(const half8*)&sAl[ar * LDK + fk];
            int bc = wc * 64 + i * 16 + fr;
            bh[i] = *(const half8*)&sBh[bc * LDK + fk];
            bl[i] = *(const half8*)&sBl[bc * LDK + fk];
        }
#pragma unroll
        for (int i = 0; i < 4; ++i)
#pragma unroll
            for (int j = 0; j < 4; ++j) {
                acc[i][j] = __builtin_amdgcn_mfma_f32_16x16x32_f16(ah[i], bh[j], acc[i][j], 0, 0, 0);
                acc[i][j] = __builtin_amdgcn_mfma_f32_16x16x32_f16(ah[i], bl[j], acc[i][j], 0, 0, 0);
                acc[i][j] = __builtin_amdgcn_mfma_f32_16x16x32_f16(al[i], bh[j], acc[i][j], 0, 0, 0);
            }
        __syncthreads();
    }

    // epilogue: C/D layout col=lane&15, row=(lane>>4)*4+reg
    int rbase = (lane >> 4) * 4;
#pragma unroll
    for (int i = 0; i < 4; ++i)
#pragma unroll
        for (int j = 0; j < 4; ++j) {
            int col = n0 + wc * 64 + j * 16 + fr;
#pragma unroll
            for (int r = 0; r < 4; ++r) {
                int row = m0 + wr * 64 + i * 16 + rbase + r;
                atomicAdd(&Cacc[(size_t)row * N + col], acc[i][j][r]);
            }
        }
}

// ---------------------------------------------------------------------------
// Split-K tiled fp32 GEMM with optional fused A-side bias+ReLU (FC1/heads):
//   Cacc[M,N] += (relu(A + abias[k]) if abias else A)[M,K] @ B[K,N]
// ---------------------------------------------------------------------------
__global__ __launch_bounds__(256) void gemm_splitk_k(const float* __restrict__ A,
                                                     const float* __restrict__ B,
                                                     const float* __restrict__ abias,
                                                     float* __restrict__ Cacc,
                                                     int M, int N, int K, int Kc)
{
    __shared__ float Ast[16][68];
    __shared__ float Bs[16][68];

    int m0 = blockIdx.y * 64, n0 = blockIdx.x * 64;
    int kb = blockIdx.z * Kc;
    int ke = min(K, kb + Kc);
    int tid = threadIdx.x;
    int tx = tid & 15, ty = tid >> 4;
    int arow = tid >> 2, akq = (tid & 3) << 2;
    int bcol = tid & 63, bk = tid >> 6;

    const float* Arow = A + (size_t)(m0 + arow) * K;
    bool nfull = (n0 + 64 <= N);

    float acc[4][4] = {};

    for (int k0 = kb; k0 < ke; k0 += 16) {
        float4 av = *(const float4*)(Arow + k0 + akq);
        if (abias) {
            av.x = fmaxf(av.x + abias[k0 + akq + 0], 0.0f);
            av.y = fmaxf(av.y + abias[k0 + akq + 1], 0.0f);
            av.z = fmaxf(av.z + abias[k0 + akq + 2], 0.0f);
            av.w = fmaxf(av.w + abias[k0 + akq + 3], 0.0f);
        }
        float bv[4];
        if (nfull) {
#pragma unroll
            for (int e = 0; e < 4; ++e)
                bv[e] = B[(size_t)(k0 + bk * 4 + e) * N + n0 + bcol];
        } else {
            bool ok = (n0 + bcol) < N;
#pragma unroll
            for (int e = 0; e < 4; ++e)
                bv[e] = ok ? B[(size_t)(k0 + bk * 4 + e) * N + n0 + bcol] : 0.0f;
        }
        __syncthreads();
        Ast[akq + 0][arow] = av.x;
        Ast[akq + 1][arow] = av.y;
        Ast[akq + 2][arow] = av.z;
        Ast[akq + 3][arow] = av.w;
#pragma unroll
        for (int e = 0; e < 4; ++e) Bs[bk * 4 + e][bcol] = bv[e];
        __syncthreads();

#pragma unroll
        for (int kk = 0; kk < 16; ++kk) {
            float4 af = *(const float4*)&Ast[kk][ty * 4];
            float4 bf = *(const float4*)&Bs[kk][tx * 4];
            float a_[4] = {af.x, af.y, af.z, af.w};
            float b_[4] = {bf.x, bf.y, bf.z, bf.w};
#pragma unroll
            for (int i = 0; i < 4; ++i)
#pragma unroll
                for (int j = 0; j < 4; ++j)
                    acc[i][j] = fmaf(a_[i], b_[j], acc[i][j]);
        }
    }

#pragma unroll
    for (int i = 0; i < 4; ++i) {
        int row = m0 + ty * 4 + i;
#pragma unroll
        for (int j = 0; j < 4; ++j) {
            int col = n0 + tx * 4 + j;
            if (col < N) atomicAdd(&Cacc[(size_t)row * N + col], acc[i][j]);
        }
    }
}

// ---------------------------------------------------------------------------
// softmax over (logits + bc), classes 1..80. grid = R, block = 64.
// ---------------------------------------------------------------------------
__global__ void softmax_k(const float* __restrict__ logits,
                          const float* __restrict__ bc,
                          float* __restrict__ scr)
{
    int r = blockIdx.x;
    int t = threadIdx.x;
    const float* row = logits + (size_t)r * NCLS;

    float v0 = row[t] + bc[t];
    float v1 = (t + 64 < NCLS) ? (row[t + 64] + bc[t + 64]) : -INFINITY;
    float m = fmaxf(v0, v1);
#pragma unroll
    for (int o = 32; o > 0; o >>= 1) m = fmaxf(m, __shfl_down(m, o));
    m = __shfl(m, 0);

    float e0 = expf(v0 - m);
    float e1 = (t + 64 < NCLS) ? expf(v1 - m) : 0.0f;
    float sum = e0 + e1;
#pragma unroll
    for (int o = 32; o > 0; o >>= 1) sum += __shfl_down(sum, o);
    sum = __shfl(sum, 0);
    float inv = 1.0f / sum;

    if (t >= 1)        scr[(size_t)r * DCLS + (t - 1)]  = e0 * inv;
    if (t + 64 < NCLS) scr[(size_t)r * DCLS + (t + 63)] = e1 * inv;
}

// ---------------------------------------------------------------------------
// box decode + validity (br fused).
// ---------------------------------------------------------------------------
__global__ void decode_k(const float* __restrict__ prop,
                         const int* __restrict__ imidx,
                         const float* __restrict__ reg,
                         const float* __restrict__ br,
                         const float* __restrict__ scr,
                         const float* __restrict__ imsz,
                         const float* __restrict__ score_thr_p,
                         const float* __restrict__ min_size_p,
                         float* __restrict__ boxes,
                         float* __restrict__ bo,
                         float* __restrict__ area,
                         float* __restrict__ smask,
                         int M)
{
    int j = blockIdx.x * blockDim.x + threadIdx.x;
    if (j >= M) return;
    int r = j / DCLS;
    int d = j - r * DCLS;
    int cls = d + 1;

    const float* pr = prop + (size_t)r * 4;
    float pw = pr[2] - pr[0], ph = pr[3] - pr[1];
    float cx = (pr[0] + pr[2]) * 0.5f, cy = (pr[1] + pr[3]) * 0.5f;

    const float* rg = reg + (size_t)r * (NCLS * 4) + cls * 4;
    const float* bb = br + cls * 4;
    float dx = (rg[0] + bb[0]) * 0.1f;
    float dy = (rg[1] + bb[1]) * 0.1f;
    float dw = fminf((rg[2] + bb[2]) * 0.2f, FLOG_MAX);
    float dh = fminf((rg[3] + bb[3]) * 0.2f, FLOG_MAX);

    float ncx = dx * pw + cx;
    float ncy = dy * ph + cy;
    float nw = expf(dw) * pw;
    float nh = expf(dh) * ph;

    int ii = imidx[r];
    float hb = imsz[ii * 2 + 0];
    float wb = imsz[ii * 2 + 1];

    float bx1 = fminf(fmaxf(ncx - nw * 0.5f, 0.0f), wb);
    float bx2 = fminf(fmaxf(ncx + nw * 0.5f, 0.0f), wb);
    float by1 = fminf(fmaxf(ncy - nh * 0.5f, 0.0f), hb);
    float by2 = fminf(fmaxf(ncy + nh * 0.5f, 0.0f), hb);

    float s = scr[j];
    bool valid = (s > score_thr_p[0]) && (bx2 - bx1 >= min_size_p[0]) && (by2 - by1 >= min_size_p[0]);

    float immax = fmaxf(fmaxf(imsz[0], imsz[1]), fmaxf(imsz[2], imsz[3]));
    float off = (float)cls * (immax + 2.0f);

    boxes[(size_t)j * 4 + 0] = bx1;
    boxes[(size_t)j * 4 + 1] = by1;
    boxes[(size_t)j * 4 + 2] = bx2;
    boxes[(size_t)j * 4 + 3] = by2;
    bo[(size_t)j * 4 + 0] = bx1 + off;
    bo[(size_t)j * 4 + 1] = by1 + off;
    bo[(size_t)j * 4 + 2] = bx2 + off;
    bo[(size_t)j * 4 + 3] = by2 + off;
    area[j] = (bx2 - bx1) * (by2 - by1);
    smask[j] = valid ? s : -1.0f;
}

// ---------------------------------------------------------------------------
// per-image NMS. grid = n, block = 1024.
// ---------------------------------------------------------------------------
#define NMS_T 1024
__global__ __launch_bounds__(NMS_T) void nms_k(const float* __restrict__ smask,
                                               const float* __restrict__ bo,
                                               const float* __restrict__ area,
                                               const float* __restrict__ boxes,
                                               const int* __restrict__ imidx,
                                               const float* __restrict__ iou_thr_p,
                                               int* __restrict__ cidx,
                                               float* __restrict__ cscore,
                                               float* __restrict__ cbo,
                                               float* __restrict__ carea,
                                               float* __restrict__ out,
                                               int M, int n, int imtop)
{
    int img = blockIdx.x;
    int t = threadIdx.x;
    const int T = NMS_T;

    __shared__ int cnt;
    __shared__ float rs[NMS_T];
    __shared__ int rg[NMS_T];
    __shared__ int rl[NMS_T];
    __shared__ float wb0, wb1, wb2, wb3, wa;

    if (t == 0) cnt = 0;
    __syncthreads();

    int base = img * M;
    for (int j = t; j < M; j += T) {
        if (imidx[j / DCLS] == img && smask[j] > 0.0f) {
            int p = atomicAdd(&cnt, 1);
            cidx[base + p] = j;
            cscore[base + p] = smask[j];
            cbo[(size_t)(base + p) * 4 + 0] = bo[(size_t)j * 4 + 0];
            cbo[(size_t)(base + p) * 4 + 1] = bo[(size_t)j * 4 + 1];
            cbo[(size_t)(base + p) * 4 + 2] = bo[(size_t)j * 4 + 2];
            cbo[(size_t)(base + p) * 4 + 3] = bo[(size_t)j * 4 + 3];
            carea[base + p] = area[j];
        }
    }
    __syncthreads();
    int K = cnt;
    float iou_thr = iou_thr_p[0];

    float* ob  = out;
    float* osc = out + (size_t)n * imtop * 4;
    float* ocl = out + (size_t)n * imtop * 5;

    int it = 0;
    for (; it < imtop; ++it) {
        float best = -1e30f; int bg = 0x7fffffff; int bl = -1;
        for (int p = t; p < K; p += T) {
            float sv = cscore[base + p];
            int g = cidx[base + p];
            if (sv > best || (sv == best && g < bg)) { best = sv; bg = g; bl = p; }
        }
        rs[t] = best; rg[t] = bg; rl[t] = bl;
        __syncthreads();
        for (int o = T / 2; o > 0; o >>= 1) {
            if (t < o) {
                if (rs[t + o] > rs[t] || (rs[t + o] == rs[t] && rg[t + o] < rg[t])) {
                    rs[t] = rs[t + o]; rg[t] = rg[t + o]; rl[t] = rl[t + o];
                }
            }
            __syncthreads();
        }
        float s = rs[0]; int g = rg[0]; int lp = rl[0];
        if (s <= 0.0f) break;

        if (t == 0) {
            size_t oslot = (size_t)img * imtop + it;
            ob[oslot * 4 + 0] = boxes[(size_t)g * 4 + 0];
            ob[oslot * 4 + 1] = boxes[(size_t)g * 4 + 1];
            ob[oslot * 4 + 2] = boxes[(size_t)g * 4 + 2];
            ob[oslot * 4 + 3] = boxes[(size_t)g * 4 + 3];
            osc[oslot] = s;
            ocl[oslot] = (float)(g % DCLS + 1);
            wb0 = cbo[(size_t)(base + lp) * 4 + 0];
            wb1 = cbo[(size_t)(base + lp) * 4 + 1];
            wb2 = cbo[(size_t)(base + lp) * 4 + 2];
            wb3 = cbo[(size_t)(base + lp) * 4 + 3];
            wa  = carea[base + lp];
            cscore[base + lp] = -1.0f;
        }
        __syncthreads();
        float b0 = wb0, b1 = wb1, b2 = wb2, b3 = wb3, ai = wa;
        for (int p = t; p < K; p += T) {
            float c0 = cbo[(size_t)(base + p) * 4 + 0];
            float c1 = cbo[(size_t)(base + p) * 4 + 1];
            float c2 = cbo[(size_t)(base + p) * 4 + 2];
            float c3 = cbo[(size_t)(base + p) * 4 + 3];
            float iw = fmaxf(fminf(b2, c2) - fmaxf(b0, c0), 0.0f);
            float ih = fmaxf(fminf(b3, c3) - fmaxf(b1, c1), 0.0f);
            float inter = iw * ih;
            float iou = inter / (ai + carea[base + p] - inter + 1e-6f);
            if (iou > iou_thr) cscore[base + p] = -1.0f;
        }
        __syncthreads();
    }

    for (int q = it + t; q < imtop; q += T) {
        size_t oslot = (size_t)img * imtop + q;
        ob[oslot * 4 + 0] = 0.0f;
        ob[oslot * 4 + 1] = 0.0f;
        ob[oslot * 4 + 2] = 0.0f;
        ob[oslot * 4 + 3] = 0.0f;
        osc[oslot] = 0.0f;
        ocl[oslot] = -1.0f;
    }
}

// ---------------------------------------------------------------------------
extern "C" void kernel_launch(void* const* d_in, const int* in_sizes, int n_in,
                              void* d_out, int out_size, void* d_ws, size_t ws_size,
                              hipStream_t stream)
{
    const float* prop   = (const float*)d_in[0];
    const int*   imidx  = (const int*)d_in[1];
    const float* f0     = (const float*)d_in[2];
    const float* f1     = (const float*)d_in[3];
    const float* f2     = (const float*)d_in[4];
    const float* f3     = (const float*)d_in[5];
    const float* W0     = (const float*)d_in[6];
    const float* b0     = (const float*)d_in[7];
    const float* W1     = (const float*)d_in[8];
    const float* b1     = (const float*)d_in[9];
    const float* Wc     = (const float*)d_in[10];
    const float* bc     = (const float*)d_in[11];
    const float* Wr     = (const float*)d_in[12];
    const float* br     = (const float*)d_in[13];
    const float* imsz   = (const float*)d_in[14];
    const float* sthr   = (const float*)d_in[15];
    const float* ithr   = (const float*)d_in[16];
    const float* msz    = (const float*)d_in[18];

    int R = in_sizes[1];              // 1024
    int n = in_sizes[14] / 2;         // 2
    int imtop = out_size / (n * 6);   // 100
    int M = R * DCLS;                 // 81920
    int K0 = NPOOL * NPOOL * CCH;     // 12544
    int CL = in_sizes[7];             // 1024

    int h0 = (int)(sqrtf((float)(in_sizes[2] / (n * CCH))) + 0.5f);
    int h1 = (int)(sqrtf((float)(in_sizes[3] / (n * CCH))) + 0.5f);
    int h2 = (int)(sqrtf((float)(in_sizes[4] / (n * CCH))) + 0.5f);
    int h3 = (int)(sqrtf((float)(in_sizes[5] / (n * CCH))) + 0.5f);

    float* outf = (float*)d_out;

    // ---- MFMA-path workspace layout (bytes) ----
    size_t szPool = (size_t)R * K0 * sizeof(_Float16);   // 25.69 MB each
    size_t szW0t  = (size_t)K0 * CL * sizeof(_Float16);  // 25.69 MB each
    size_t needed = 4 * szPool                            // poolH,poolL,W0tH,W0tL (szPool==szW0t)
                  + (size_t)R * CL * 4 * 2                // x0acc, x1acc
                  + (size_t)R * NCLS * 4                  // logits
                  + (size_t)R * NCLS * 4 * 4              // reg
                  + (size_t)R * DCLS * 4;                 // scr

    bool mfma_ok = (ws_size >= needed) && (R % 128 == 0) && (CL % 128 == 0) && (K0 % 64 == 0);

    if (mfma_ok) {
        uint8_t* w = (uint8_t*)d_ws;
        size_t o = 0;
        _Float16* poolH = (_Float16*)(w + o); o += szPool;
        _Float16* poolL = (_Float16*)(w + o); o += szPool;
        _Float16* W0tH  = (_Float16*)(w + o); o += szW0t;
        _Float16* W0tL  = (_Float16*)(w + o); o += szW0t;
        float* x0acc  = (float*)(w + o); o += (size_t)R * CL * 4;
        float* x1acc  = (float*)(w + o); o += (size_t)R * CL * 4;
        float* logits = (float*)(w + o); o += (size_t)R * NCLS * 4;
        float* reg    = (float*)(w + o); o += (size_t)R * NCLS * 4 * 4;
        float* scr    = (float*)(w + o);

        // decode/NMS arrays alias the pool region (dead after FC0)
        float* boxes = (float*)d_ws;
        float* bo    = boxes + (size_t)M * 4;
        float* area  = bo + (size_t)M * 4;
        float* smask = area + M;
        int*   cidx  = (int*)(smask + M);
        float* cscore = (float*)(cidx + (size_t)n * M);
        float* cbo   = cscore + (size_t)n * M;
        float* carea = cbo + (size_t)n * M * 4;

        // 0. zero accumulators (x0acc..reg contiguous)
        {
            size_t zbytes = (size_t)R * CL * 4 * 2 + (size_t)R * NCLS * 4 + (size_t)R * NCLS * 4 * 4;
            int c4 = (int)(zbytes / 16);
            zero_k<<<dim3((c4 + 255) / 256), dim3(256), 0, stream>>>((float4*)x0acc, c4);
        }
        // 1. transpose-convert W0 -> W0t hi/lo   (grid K0/64 x CL/64)
        convert_w_t_k<<<dim3(K0 / 64, CL / 64), dim3(256), 0, stream>>>(W0, W0tH, W0tL, K0, CL);
        // 2. RoI align -> f16 hi/lo pooled
        roi_align_f16_k<<<dim3(R * 49), dim3(256), 0, stream>>>(
            prop, imidx, f0, f1, f2, f3, h0, h1, h2, h3, poolH, poolL);
        // 3. FC0 via split-f16 MFMA, split-K=14 (Kc=896, 28 BK-steps) -> 896 blocks
        gemm_mfma_split_k<<<dim3(CL / 128, R / 128, 14), dim3(256), 0, stream>>>(
            poolH, poolL, W0tH, W0tL, x0acc, R, CL, K0, K0 / 14);
        // 4. FC1 fp32: x1acc = relu(x0acc + b0) @ W1
        gemm_splitk_k<<<dim3(CL / 64, R / 64, 4), dim3(256), 0, stream>>>(
            x0acc, W1, b0, x1acc, R, CL, CL, 256);
        // 5. heads
        gemm_splitk_k<<<dim3((NCLS + 63) / 64, R / 64, 8), dim3(256), 0, stream>>>(
            x1acc, Wc, b1, logits, R, NCLS, CL, 128);
        gemm_splitk_k<<<dim3((NCLS * 4 + 63) / 64, R / 64, 4), dim3(256), 0, stream>>>(
            x1acc, Wr, b1, reg, R, NCLS * 4, CL, 256);
        // 6. softmax + decode
        softmax_k<<<dim3(R), dim3(64), 0, stream>>>(logits, bc, scr);
        decode_k<<<dim3((M + 255) / 256), dim3(256), 0, stream>>>(
            prop, imidx, reg, br, scr, imsz, sthr, msz, boxes, bo, area, smask, M);
        // 7. NMS
        nms_k<<<dim3(n), dim3(NMS_T), 0, stream>>>(
            smask, bo, area, boxes, imidx, ithr,
            cidx, cscore, cbo, carea, outf, M, n, imtop);
    } else {
        // -------- fallback: R2 all-fp32 pipeline --------
        float* ws = (float*)d_ws;
        size_t off = 0;
        float* pooled  = ws + off; off += (size_t)R * K0;
        float* x0acc   = ws + off; off += (size_t)R * CL;
        float* x1acc   = ws + off; off += (size_t)R * CL;
        float* logits  = ws + off; off += (size_t)R * NCLS;
        off = (off + 3) & ~(size_t)3;
        float* reg     = ws + off; off += (size_t)R * NCLS * 4;
        float* scr     = ws + off; off += (size_t)R * DCLS;

        float* boxes = ws;
        float* bo    = boxes + (size_t)M * 4;
        float* area  = bo + (size_t)M * 4;
        float* smask = area + M;
        int*   cidx  = (int*)(smask + M);
        float* cscore = (float*)(cidx + (size_t)n * M);
        float* cbo   = cscore + (size_t)n * M;
        float* carea = cbo + (size_t)n * M * 4;

        {
            size_t zcount = (size_t)(reg + (size_t)R * NCLS * 4 - x0acc);
            int c4 = (int)(zcount / 4);
            zero_k<<<dim3((c4 + 255) / 256), dim3(256), 0, stream>>>((float4*)x0acc, c4);
        }
        roi_align_k<<<dim3(R * 49), dim3(256), 0, stream>>>(
            prop, imidx, f0, f1, f2, f3, h0, h1, h2, h3, pooled);
        gemm_splitk_k<<<dim3(CL / 64, R / 64, 8), dim3(256), 0, stream>>>(
            pooled, W0, nullptr, x0acc, R, CL, K0, 1568);
        gemm_splitk_k<<<dim3(CL / 64, R / 64, 4), dim3(256), 0, stream>>>(
            x0acc, W1, b0, x1acc, R, CL, CL, 256);
        gemm_splitk_k<<<dim3((NCLS + 63) / 64, R / 64, 8), dim3(256), 0, stream>>>(
            x1acc, Wc, b1, logits, R, NCLS, CL, 128);
        gemm_splitk_k<<<dim3((NCLS * 4 + 63) / 64, R / 64, 4), dim3(256), 0, stream>>>(
            x1acc, Wr, b1, reg, R, NCLS * 4, CL, 256);
        softmax_k<<<dim3(R), dim3(64), 0, stream>>>(logits, bc, scr);
        decode_k<<<dim3((M + 255) / 256), dim3(256), 0, stream>>>(
            prop, imidx, reg, br, scr, imsz, sthr, msz, boxes, bo, area, smask, M);
        nms_k<<<dim3(n), dim3(NMS_T), 0, stream>>>(
            smask, bo, area, boxes, imidx, ithr,
            cidx, cscore, cbo, carea, outf, M, n, imtop);
    }
}

// Round 4
// 498.925 us; speedup vs baseline: 3.3317x; 1.0982x over previous
//
#include <hip/hip_runtime.h>
#include <math.h>

#define CCH 256
#define NPOOL 7
#define NCLS 81
#define DCLS 80
#define NHEAD 512            /* padded head width: 81 logits + 324 reg + pad */
#define FLOG_MAX 4.1351666f  /* log(1000/16) */

typedef _Float16 half8 __attribute__((ext_vector_type(8)));
typedef _Float16 half4 __attribute__((ext_vector_type(4)));
typedef float floatx4 __attribute__((ext_vector_type(4)));

// ---------------------------------------------------------------------------
// zero a region (float4 stores)
// ---------------------------------------------------------------------------
__global__ void zero_k(float4* __restrict__ p, int count4)
{
    int i = blockIdx.x * blockDim.x + threadIdx.x;
    if (i < count4) p[i] = make_float4(0.f, 0.f, 0.f, 0.f);
}

// ---------------------------------------------------------------------------
// RoI-align box math (per-block scalar part)
// ---------------------------------------------------------------------------
__device__ __forceinline__ void roi_setup(
    const float* __restrict__ prop, const int* __restrict__ imidx,
    const float* __restrict__ f0, const float* __restrict__ f1,
    const float* __restrict__ f2, const float* __restrict__ f3,
    int h0, int h1, int h2, int h3, int b,
    const float*& base, int& W, size_t& o00, size_t& o01, size_t& o10, size_t& o11,
    float& w00, float& w01, float& w10, float& w11)
{
    int roi = b / 49, p = b % 49;
    int py = p / 7, px = p % 7;

    const float* pr = prop + (size_t)roi * 4;
    float x1 = pr[0], y1 = pr[1], x2 = pr[2], y2 = pr[3];
    float pw = x2 - x1, ph = y2 - y1;

    float lv = floorf(4.0f + log2f(sqrtf(pw * ph) / 224.0f + 1e-6f));
    lv = fminf(fmaxf(lv, 2.0f), 5.0f);
    int lvl = (int)lv - 2;

    const float* fm; int H; float s;
    if (lvl == 0)      { fm = f0; H = h0; s = 0.25f;    }
    else if (lvl == 1) { fm = f1; H = h1; s = 0.125f;   }
    else if (lvl == 2) { fm = f2; H = h2; s = 0.0625f;  }
    else               { fm = f3; H = h3; s = 0.03125f; }
    W = H;

    float xs1 = x1 * s, ys1 = y1 * s, xs2 = x2 * s, ys2 = y2 * s;
    float gx = (px + 0.5f) / 7.0f, gy = (py + 0.5f) / 7.0f;
    float xx = xs1 + gx * (xs2 - xs1) - 0.5f;
    float yy = ys1 + gy * (ys2 - ys1) - 0.5f;
    float x0f = floorf(xx), y0f = floorf(yy);
    float wx = xx - x0f, wy = yy - y0f;
    int x0i = min(max((int)x0f, 0), W - 1);
    int x1i = min(max((int)x0f + 1, 0), W - 1);
    int y0i = min(max((int)y0f, 0), H - 1);
    int y1i = min(max((int)y0f + 1, 0), H - 1);

    int ii = imidx[roi];
    base = fm + (size_t)ii * H * W * CCH;
    o00 = ((size_t)y0i * W + x0i) * CCH;
    o01 = ((size_t)y0i * W + x1i) * CCH;
    o10 = ((size_t)y1i * W + x0i) * CCH;
    o11 = ((size_t)y1i * W + x1i) * CCH;
    w00 = (1.0f - wx) * (1.0f - wy);
    w01 = wx * (1.0f - wy);
    w10 = (1.0f - wx) * wy;
    w11 = wx * wy;
}

// fp32 fallback variant: grid R*49 x 256 threads
__global__ void roi_align_k(const float* __restrict__ prop,
                            const int* __restrict__ imidx,
                            const float* __restrict__ f0,
                            const float* __restrict__ f1,
                            const float* __restrict__ f2,
                            const float* __restrict__ f3,
                            int h0, int h1, int h2, int h3,
                            float* __restrict__ pooled)
{
    int b = blockIdx.x, c = threadIdx.x;
    const float* base; int W; size_t o00, o01, o10, o11;
    float w00, w01, w10, w11;
    roi_setup(prop, imidx, f0, f1, f2, f3, h0, h1, h2, h3, b,
              base, W, o00, o01, o10, o11, w00, w01, w10, w11);
    float v = base[o00 + c] * w00 + base[o01 + c] * w01
            + base[o10 + c] * w10 + base[o11 + c] * w11;
    pooled[(size_t)b * CCH + c] = v;
}

// f16 hi/lo split, vectorized: grid R*49 x 64 threads (4 ch/thread)
__global__ __launch_bounds__(64) void roi_align_f16v_k(
    const float* __restrict__ prop, const int* __restrict__ imidx,
    const float* __restrict__ f0, const float* __restrict__ f1,
    const float* __restrict__ f2, const float* __restrict__ f3,
    int h0, int h1, int h2, int h3,
    _Float16* __restrict__ poolH, _Float16* __restrict__ poolL)
{
    int b = blockIdx.x;
    const float* base; int W; size_t o00, o01, o10, o11;
    float w00, w01, w10, w11;
    roi_setup(prop, imidx, f0, f1, f2, f3, h0, h1, h2, h3, b,
              base, W, o00, o01, o10, o11, w00, w01, w10, w11);

    int c4 = threadIdx.x * 4;
    float4 v00 = *(const float4*)(base + o00 + c4);
    float4 v01 = *(const float4*)(base + o01 + c4);
    float4 v10 = *(const float4*)(base + o10 + c4);
    float4 v11 = *(const float4*)(base + o11 + c4);
    const float* p00 = (const float*)&v00;
    const float* p01 = (const float*)&v01;
    const float* p10 = (const float*)&v10;
    const float* p11 = (const float*)&v11;

    half4 h, l;
#pragma unroll
    for (int e = 0; e < 4; ++e) {
        float v = p00[e] * w00 + p01[e] * w01 + p10[e] * w10 + p11[e] * w11;
        _Float16 hh = (_Float16)v;
        h[e] = hh;
        l[e] = (_Float16)(v - (float)hh);
    }
    size_t idx = (size_t)b * CCH + c4;
    *(half4*)(poolH + idx) = h;
    *(half4*)(poolL + idx) = l;
}

// ---------------------------------------------------------------------------
// Transpose-convert: W [K][N] fp32 -> WtH/WtL [N][K] f16 hi/lo.
// grid = (K/64, N/64), block = 256. K%64==0, N%64==0 required.
// ---------------------------------------------------------------------------
__global__ __launch_bounds__(256) void convert_w_t_k(const float* __restrict__ W,
                                                     _Float16* __restrict__ WtH,
                                                     _Float16* __restrict__ WtL,
                                                     int K, int N)
{
    __shared__ float sh[64][65];
    int k0 = blockIdx.x * 64, n0 = blockIdx.y * 64;
    int t = threadIdx.x;
#pragma unroll
    for (int p = 0; p < 4; ++p) {
        int idx = p * 256 + t;
        int kr = idx >> 4, nc = (idx & 15) * 4;
        float4 v = *(const float4*)(W + (size_t)(k0 + kr) * N + n0 + nc);
        sh[kr][nc + 0] = v.x; sh[kr][nc + 1] = v.y;
        sh[kr][nc + 2] = v.z; sh[kr][nc + 3] = v.w;
    }
    __syncthreads();
#pragma unroll
    for (int p = 0; p < 4; ++p) {
        int idx = p * 256 + t;
        int nr = idx >> 4, kc = (idx & 15) * 4;
        half4 h, l;
#pragma unroll
        for (int i = 0; i < 4; ++i) {
            float v = sh[kc + i][nr];
            _Float16 hh = (_Float16)v;
            h[i] = hh;
            l[i] = (_Float16)(v - (float)hh);
        }
        *(half4*)(WtH + (size_t)(n0 + nr) * K + k0 + kc) = h;
        *(half4*)(WtL + (size_t)(n0 + nr) * K + k0 + kc) = l;
    }
}

// Guarded variant for N not multiple of 64; writes rows rowofs+n with stride Kt.
__global__ __launch_bounds__(256) void convert_w_t_guard_k(const float* __restrict__ W,
                                                           _Float16* __restrict__ WtH,
                                                           _Float16* __restrict__ WtL,
                                                           int K, int N, int Kt, int rowofs)
{
    __shared__ float sh[64][65];
    int k0 = blockIdx.x * 64, n0 = blockIdx.y * 64;
    int t = threadIdx.x;
#pragma unroll
    for (int p = 0; p < 4; ++p) {
        int idx = p * 256 + t;
        int kr = idx >> 4, nc = (idx & 15) * 4;
#pragma unroll
        for (int e = 0; e < 4; ++e) {
            int nn = n0 + nc + e;
            sh[kr][nc + e] = (nn < N) ? W[(size_t)(k0 + kr) * N + nn] : 0.0f;
        }
    }
    __syncthreads();
#pragma unroll
    for (int p = 0; p < 4; ++p) {
        int idx = p * 256 + t;
        int nr = idx >> 4, kc = (idx & 15) * 4;
        if (n0 + nr < N) {
            half4 h, l;
#pragma unroll
            for (int i = 0; i < 4; ++i) {
                float v = sh[kc + i][nr];
                _Float16 hh = (_Float16)v;
                h[i] = hh;
                l[i] = (_Float16)(v - (float)hh);
            }
            *(half4*)(WtH + (size_t)(rowofs + n0 + nr) * Kt + k0 + kc) = h;
            *(half4*)(WtL + (size_t)(rowofs + n0 + nr) * Kt + k0 + kc) = l;
        }
    }
}

// ---------------------------------------------------------------------------
// act-split: out = relu(acc + bias) -> f16 hi/lo. 4 elems/thread.
// ---------------------------------------------------------------------------
__global__ void act_split_k(const float* __restrict__ acc,
                            const float* __restrict__ bias,
                            _Float16* __restrict__ outH,
                            _Float16* __restrict__ outL,
                            int total, int CL)
{
    int i = (blockIdx.x * blockDim.x + threadIdx.x) * 4;
    if (i >= total) return;
    int b = i % CL;
    float4 v = *(const float4*)(acc + i);
    float4 bb = *(const float4*)(bias + b);
    const float* pv = (const float*)&v;
    const float* pb = (const float*)&bb;
    half4 h, l;
#pragma unroll
    for (int e = 0; e < 4; ++e) {
        float f = fmaxf(pv[e] + pb[e], 0.0f);
        _Float16 hh = (_Float16)f;
        h[e] = hh;
        l[e] = (_Float16)(f - (float)hh);
    }
    *(half4*)(outH + i) = h;
    *(half4*)(outL + i) = l;
}

// ---------------------------------------------------------------------------
// Split-f16 MFMA GEMM, B direct-from-global:
//   Cacc[M,N] += (Ah+Al)[M][K] @ (Bh+Bl)^T  with Bt given as [N][K].
// 128x128 block tile, BK=32, 256 thr (4 waves, 64x64 each = 4x4 of
// 16x16x32 f16 MFMA). Only A staged in LDS (18 KB); B fragments loaded
// straight from global (k-contiguous half8, L2-resident per split slice).
// Split-K via blockIdx.z; fp32 atomicAdd epilogue (Cacc pre-zeroed).
// M%128==0, N%128==0, Kc%32==0 required.
// ---------------------------------------------------------------------------
#define LDK 36
__global__ __launch_bounds__(256) void gemm_mfma_split_k(
    const _Float16* __restrict__ Ah, const _Float16* __restrict__ Al,
    const _Float16* __restrict__ Bh, const _Float16* __restrict__ Bl,
    float* __restrict__ Cacc, int M, int N, int K, int Kc)
{
    __shared__ _Float16 sAh[128 * LDK], sAl[128 * LDK];

    int m0 = blockIdx.y * 128, n0 = blockIdx.x * 128;
    int kb = blockIdx.z * Kc;
    int ke = min(K, kb + Kc);
    int t = threadIdx.x;
    int lane = t & 63, w = t >> 6;
    int wr = w >> 1, wc = w & 1;          // 2x2 wave grid over 128x128
    int srow = t >> 2, skq = (t & 3) * 8; // A staging: 4 thr x 16B per row
    int fr = lane & 15;                   // fragment row/col within 16
    int fk = (lane >> 4) * 8;             // fragment k offset

    // B fragment base pointers (k-contiguous in global Bt[N][K])
    const _Float16* bhp[4];
    const _Float16* blp[4];
#pragma unroll
    for (int j = 0; j < 4; ++j) {
        int col = n0 + wc * 64 + j * 16 + fr;
        bhp[j] = Bh + (size_t)col * K + fk;
        blp[j] = Bl + (size_t)col * K + fk;
    }
    const _Float16* a0p = Ah + (size_t)(m0 + srow) * K + skq;
    const _Float16* a1p = Al + (size_t)(m0 + srow) * K + skq;
    const _Float16* a2p = Ah + (size_t)(m0 + srow + 64) * K + skq;
    const _Float16* a3p = Al + (size_t)(m0 + srow + 64) * K + skq;

    floatx4 acc[4][4] = {};

    for (int k0 = kb; k0 < ke; k0 += 32) {
        // B fragments: direct global loads, issued first (stay in flight)
        half8 bh[4], bl[4];
#pragma unroll
        for (int j = 0; j < 4; ++j) {
            bh[j] = *(const half8*)(bhp[j] + k0);
            bl[j] = *(const half8*)(blp[j] + k0);
        }
        // A staging loads
        half8 v0 = *(const half8*)(a0p + k0);
        half8 v1 = *(const half8*)(a1p + k0);
        half8 v2 = *(const half8*)(a2p + k0);
        half8 v3 = *(const half8*)(a3p + k0);

        __syncthreads();   // prior iteration's LDS reads complete
        *(half8*)&sAh[srow * LDK + skq] = v0;
        *(half8*)&sAl[srow * LDK + skq] = v1;
        *(half8*)&sAh[(srow + 64) * LDK + skq] = v2;
        *(half8*)&sAl[(srow + 64) * LDK + skq] = v3;
        __syncthreads();

        half8 ah[4], al[4];
#pragma unroll
        for (int i = 0; i < 4; ++i) {
            int ar = wr * 64 + i * 16 + fr;
            ah[i] = *(const half8*)&sAh[ar * LDK + fk];
            al[i] = *(const half8*)&sAl[ar * LDK + fk];
        }
#pragma unroll
        for (int i = 0; i < 4; ++i)
#pragma unroll
            for (int j = 0; j < 4; ++j) {
                acc[i][j] = __builtin_amdgcn_mfma_f32_16x16x32_f16(ah[i], bh[j], acc[i][j], 0, 0, 0);
                acc[i][j] = __builtin_amdgcn_mfma_f32_16x16x32_f16(ah[i], bl[j], acc[i][j], 0, 0, 0);
                acc[i][j] = __builtin_amdgcn_mfma_f32_16x16x32_f16(al[i], bh[j], acc[i][j], 0, 0, 0);
            }
    }

    // epilogue: C/D layout col=lane&15, row=(lane>>4)*4+reg
    int rbase = (lane >> 4) * 4;
#pragma unroll
    for (int i = 0; i < 4; ++i)
#pragma unroll
        for (int j = 0; j < 4; ++j) {
            int col = n0 + wc * 64 + j * 16 + fr;
#pragma unroll
            for (int r = 0; r < 4; ++r) {
                int row = m0 + wr * 64 + i * 16 + rbase + r;
                atomicAdd(&Cacc[(size_t)row * N + col], acc[i][j][r]);
            }
        }
}

// ---------------------------------------------------------------------------
// fp32 split-K GEMM (fallback path only)
// ---------------------------------------------------------------------------
__global__ __launch_bounds__(256) void gemm_splitk_k(const float* __restrict__ A,
                                                     const float* __restrict__ B,
                                                     const float* __restrict__ abias,
                                                     float* __restrict__ Cacc,
                                                     int M, int N, int K, int Kc)
{
    __shared__ float Ast[16][68];
    __shared__ float Bs[16][68];

    int m0 = blockIdx.y * 64, n0 = blockIdx.x * 64;
    int kb = blockIdx.z * Kc;
    int ke = min(K, kb + Kc);
    int tid = threadIdx.x;
    int tx = tid & 15, ty = tid >> 4;
    int arow = tid >> 2, akq = (tid & 3) << 2;
    int bcol = tid & 63, bk = tid >> 6;

    const float* Arow = A + (size_t)(m0 + arow) * K;
    bool nfull = (n0 + 64 <= N);

    float acc[4][4] = {};

    for (int k0 = kb; k0 < ke; k0 += 16) {
        float4 av = *(const float4*)(Arow + k0 + akq);
        if (abias) {
            av.x = fmaxf(av.x + abias[k0 + akq + 0], 0.0f);
            av.y = fmaxf(av.y + abias[k0 + akq + 1], 0.0f);
            av.z = fmaxf(av.z + abias[k0 + akq + 2], 0.0f);
            av.w = fmaxf(av.w + abias[k0 + akq + 3], 0.0f);
        }
        float bv[4];
        if (nfull) {
#pragma unroll
            for (int e = 0; e < 4; ++e)
                bv[e] = B[(size_t)(k0 + bk * 4 + e) * N + n0 + bcol];
        } else {
            bool ok = (n0 + bcol) < N;
#pragma unroll
            for (int e = 0; e < 4; ++e)
                bv[e] = ok ? B[(size_t)(k0 + bk * 4 + e) * N + n0 + bcol] : 0.0f;
        }
        __syncthreads();
        Ast[akq + 0][arow] = av.x;
        Ast[akq + 1][arow] = av.y;
        Ast[akq + 2][arow] = av.z;
        Ast[akq + 3][arow] = av.w;
#pragma unroll
        for (int e = 0; e < 4; ++e) Bs[bk * 4 + e][bcol] = bv[e];
        __syncthreads();

#pragma unroll
        for (int kk = 0; kk < 16; ++kk) {
            float4 af = *(const float4*)&Ast[kk][ty * 4];
            float4 bf = *(const float4*)&Bs[kk][tx * 4];
            float a_[4] = {af.x, af.y, af.z, af.w};
            float b_[4] = {bf.x, bf.y, bf.z, bf.w};
#pragma unroll
            for (int i = 0; i < 4; ++i)
#pragma unroll
                for (int j = 0; j < 4; ++j)
                    acc[i][j] = fmaf(a_[i], b_[j], acc[i][j]);
        }
    }

#pragma unroll
    for (int i = 0; i < 4; ++i) {
        int row = m0 + ty * 4 + i;
#pragma unroll
        for (int j = 0; j < 4; ++j) {
            int col = n0 + tx * 4 + j;
            if (col < N) atomicAdd(&Cacc[(size_t)row * N + col], acc[i][j]);
        }
    }
}

// ---------------------------------------------------------------------------
// softmax over (logits + bc), classes 1..80. grid = R, block = 64.
// logits row stride = ldl.
// ---------------------------------------------------------------------------
__global__ void softmax_k(const float* __restrict__ logits, int ldl,
                          const float* __restrict__ bc,
                          float* __restrict__ scr)
{
    int r = blockIdx.x;
    int t = threadIdx.x;
    const float* row = logits + (size_t)r * ldl;

    float v0 = row[t] + bc[t];
    float v1 = (t + 64 < NCLS) ? (row[t + 64] + bc[t + 64]) : -INFINITY;
    float m = fmaxf(v0, v1);
#pragma unroll
    for (int o = 32; o > 0; o >>= 1) m = fmaxf(m, __shfl_down(m, o));
    m = __shfl(m, 0);

    float e0 = expf(v0 - m);
    float e1 = (t + 64 < NCLS) ? expf(v1 - m) : 0.0f;
    float sum = e0 + e1;
#pragma unroll
    for (int o = 32; o > 0; o >>= 1) sum += __shfl_down(sum, o);
    sum = __shfl(sum, 0);
    float inv = 1.0f / sum;

    if (t >= 1)        scr[(size_t)r * DCLS + (t - 1)]  = e0 * inv;
    if (t + 64 < NCLS) scr[(size_t)r * DCLS + (t + 63)] = e1 * inv;
}

// ---------------------------------------------------------------------------
// box decode + validity (br fused). reg value at head[r*ldh + regofs + cls*4 + e]
// ---------------------------------------------------------------------------
__global__ void decode_k(const float* __restrict__ prop,
                         const int* __restrict__ imidx,
                         const float* __restrict__ head, int ldh, int regofs,
                         const float* __restrict__ br,
                         const float* __restrict__ scr,
                         const float* __restrict__ imsz,
                         const float* __restrict__ score_thr_p,
                         const float* __restrict__ min_size_p,
                         float* __restrict__ boxes,
                         float* __restrict__ bo,
                         float* __restrict__ area,
                         float* __restrict__ smask,
                         int M)
{
    int j = blockIdx.x * blockDim.x + threadIdx.x;
    if (j >= M) return;
    int r = j / DCLS;
    int d = j - r * DCLS;
    int cls = d + 1;

    const float* pr = prop + (size_t)r * 4;
    float pw = pr[2] - pr[0], ph = pr[3] - pr[1];
    float cx = (pr[0] + pr[2]) * 0.5f, cy = (pr[1] + pr[3]) * 0.5f;

    const float* rg = head + (size_t)r * ldh + regofs + cls * 4;
    const float* bb = br + cls * 4;
    float dx = (rg[0] + bb[0]) * 0.1f;
    float dy = (rg[1] + bb[1]) * 0.1f;
    float dw = fminf((rg[2] + bb[2]) * 0.2f, FLOG_MAX);
    float dh = fminf((rg[3] + bb[3]) * 0.2f, FLOG_MAX);

    float ncx = dx * pw + cx;
    float ncy = dy * ph + cy;
    float nw = expf(dw) * pw;
    float nh = expf(dh) * ph;

    int ii = imidx[r];
    float hb = imsz[ii * 2 + 0];
    float wb = imsz[ii * 2 + 1];

    float bx1 = fminf(fmaxf(ncx - nw * 0.5f, 0.0f), wb);
    float bx2 = fminf(fmaxf(ncx + nw * 0.5f, 0.0f), wb);
    float by1 = fminf(fmaxf(ncy - nh * 0.5f, 0.0f), hb);
    float by2 = fminf(fmaxf(ncy + nh * 0.5f, 0.0f), hb);

    float s = scr[j];
    bool valid = (s > score_thr_p[0]) && (bx2 - bx1 >= min_size_p[0]) && (by2 - by1 >= min_size_p[0]);

    float immax = fmaxf(fmaxf(imsz[0], imsz[1]), fmaxf(imsz[2], imsz[3]));
    float off = (float)cls * (immax + 2.0f);

    boxes[(size_t)j * 4 + 0] = bx1;
    boxes[(size_t)j * 4 + 1] = by1;
    boxes[(size_t)j * 4 + 2] = bx2;
    boxes[(size_t)j * 4 + 3] = by2;
    bo[(size_t)j * 4 + 0] = bx1 + off;
    bo[(size_t)j * 4 + 1] = by1 + off;
    bo[(size_t)j * 4 + 2] = bx2 + off;
    bo[(size_t)j * 4 + 3] = by2 + off;
    area[j] = (bx2 - bx1) * (by2 - by1);
    smask[j] = valid ? s : -1.0f;
}

// ---------------------------------------------------------------------------
// per-image NMS. grid = n, block = 1024.
// ---------------------------------------------------------------------------
#define NMS_T 1024
__global__ __launch_bounds__(NMS_T) void nms_k(const float* __restrict__ smask,
                                               const float* __restrict__ bo,
                                               const float* __restrict__ area,
                                               const float* __restrict__ boxes,
                                               const int* __restrict__ imidx,
                                               const float* __restrict__ iou_thr_p,
                                               int* __restrict__ cidx,
                                               float* __restrict__ cscore,
                                               float* __restrict__ cbo,
                                               float* __restrict__ carea,
                                               float* __restrict__ out,
                                               int M, int n, int imtop)
{
    int img = blockIdx.x;
    int t = threadIdx.x;
    const int T = NMS_T;

    __shared__ int cnt;
    __shared__ float rs[NMS_T];
    __shared__ int rg[NMS_T];
    __shared__ int rl[NMS_T];
    __shared__ float wb0, wb1, wb2, wb3, wa;

    if (t == 0) cnt = 0;
    __syncthreads();

    int base = img * M;
    for (int j = t; j < M; j += T) {
        if (imidx[j / DCLS] == img && smask[j] > 0.0f) {
            int p = atomicAdd(&cnt, 1);
            cidx[base + p] = j;
            cscore[base + p] = smask[j];
            cbo[(size_t)(base + p) * 4 + 0] = bo[(size_t)j * 4 + 0];
            cbo[(size_t)(base + p) * 4 + 1] = bo[(size_t)j * 4 + 1];
            cbo[(size_t)(base + p) * 4 + 2] = bo[(size_t)j * 4 + 2];
            cbo[(size_t)(base + p) * 4 + 3] = bo[(size_t)j * 4 + 3];
            carea[base + p] = area[j];
        }
    }
    __syncthreads();
    int K = cnt;
    float iou_thr = iou_thr_p[0];

    float* ob  = out;
    float* osc = out + (size_t)n * imtop * 4;
    float* ocl = out + (size_t)n * imtop * 5;

    int it = 0;
    for (; it < imtop; ++it) {
        float best = -1e30f; int bg = 0x7fffffff; int bl = -1;
        for (int p = t; p < K; p += T) {
            float sv = cscore[base + p];
            int g = cidx[base + p];
            if (sv > best || (sv == best && g < bg)) { best = sv; bg = g; bl = p; }
        }
        rs[t] = best; rg[t] = bg; rl[t] = bl;
        __syncthreads();
        for (int o = T / 2; o > 0; o >>= 1) {
            if (t < o) {
                if (rs[t + o] > rs[t] || (rs[t + o] == rs[t] && rg[t + o] < rg[t])) {
                    rs[t] = rs[t + o]; rg[t] = rg[t + o]; rl[t] = rl[t + o];
                }
            }
            __syncthreads();
        }
        float s = rs[0]; int g = rg[0]; int lp = rl[0];
        if (s <= 0.0f) break;

        if (t == 0) {
            size_t oslot = (size_t)img * imtop + it;
            ob[oslot * 4 + 0] = boxes[(size_t)g * 4 + 0];
            ob[oslot * 4 + 1] = boxes[(size_t)g * 4 + 1];
            ob[oslot * 4 + 2] = boxes[(size_t)g * 4 + 2];
            ob[oslot * 4 + 3] = boxes[(size_t)g * 4 + 3];
            osc[oslot] = s;
            ocl[oslot] = (float)(g % DCLS + 1);
            wb0 = cbo[(size_t)(base + lp) * 4 + 0];
            wb1 = cbo[(size_t)(base + lp) * 4 + 1];
            wb2 = cbo[(size_t)(base + lp) * 4 + 2];
            wb3 = cbo[(size_t)(base + lp) * 4 + 3];
            wa  = carea[base + lp];
            cscore[base + lp] = -1.0f;
        }
        __syncthreads();
        float b0 = wb0, b1 = wb1, b2 = wb2, b3 = wb3, ai = wa;
        for (int p = t; p < K; p += T) {
            float c0 = cbo[(size_t)(base + p) * 4 + 0];
            float c1 = cbo[(size_t)(base + p) * 4 + 1];
            float c2 = cbo[(size_t)(base + p) * 4 + 2];
            float c3 = cbo[(size_t)(base + p) * 4 + 3];
            float iw = fmaxf(fminf(b2, c2) - fmaxf(b0, c0), 0.0f);
            float ih = fmaxf(fminf(b3, c3) - fmaxf(b1, c1), 0.0f);
            float inter = iw * ih;
            float iou = inter / (ai + carea[base + p] - inter + 1e-6f);
            if (iou > iou_thr) cscore[base + p] = -1.0f;
        }
        __syncthreads();
    }

    for (int q = it + t; q < imtop; q += T) {
        size_t oslot = (size_t)img * imtop + q;
        ob[oslot * 4 + 0] = 0.0f;
        ob[oslot * 4 + 1] = 0.0f;
        ob[oslot * 4 + 2] = 0.0f;
        ob[oslot * 4 + 3] = 0.0f;
        osc[oslot] = 0.0f;
        ocl[oslot] = -1.0f;
    }
}

// ---------------------------------------------------------------------------
extern "C" void kernel_launch(void* const* d_in, const int* in_sizes, int n_in,
                              void* d_out, int out_size, void* d_ws, size_t ws_size,
                              hipStream_t stream)
{
    const float* prop   = (const float*)d_in[0];
    const int*   imidx  = (const int*)d_in[1];
    const float* f0     = (const float*)d_in[2];
    const float* f1     = (const float*)d_in[3];
    const float* f2     = (const float*)d_in[4];
    const float* f3     = (const float*)d_in[5];
    const float* W0     = (const float*)d_in[6];
    const float* b0     = (const float*)d_in[7];
    const float* W1     = (const float*)d_in[8];
    const float* b1     = (const float*)d_in[9];
    const float* Wc     = (const float*)d_in[10];
    const float* bc     = (const float*)d_in[11];
    const float* Wr     = (const float*)d_in[12];
    const float* br     = (const float*)d_in[13];
    const float* imsz   = (const float*)d_in[14];
    const float* sthr   = (const float*)d_in[15];
    const float* ithr   = (const float*)d_in[16];
    const float* msz    = (const float*)d_in[18];

    int R = in_sizes[1];              // 1024
    int n = in_sizes[14] / 2;         // 2
    int imtop = out_size / (n * 6);   // 100
    int M = R * DCLS;                 // 81920
    int K0 = NPOOL * NPOOL * CCH;     // 12544
    int CL = in_sizes[7];             // 1024

    int h0 = (int)(sqrtf((float)(in_sizes[2] / (n * CCH))) + 0.5f);
    int h1 = (int)(sqrtf((float)(in_sizes[3] / (n * CCH))) + 0.5f);
    int h2 = (int)(sqrtf((float)(in_sizes[4] / (n * CCH))) + 0.5f);
    int h3 = (int)(sqrtf((float)(in_sizes[5] / (n * CCH))) + 0.5f);

    float* outf = (float*)d_out;

    // ---- MFMA-path workspace layout (bytes) ----
    size_t szPool  = (size_t)R * K0 * 2;        // 25.69 MB each (poolH/L, W0tH/L)
    size_t szX     = (size_t)R * CL * 4;        // 4 MB
    size_t szHead  = (size_t)R * NHEAD * 4;     // 2 MB
    size_t szWh    = (size_t)NHEAD * CL * 2;    // 1 MB each
    size_t szXh    = (size_t)R * CL * 2;        // 2 MB each
    size_t szW1t   = (size_t)CL * CL * 2;       // 2 MB each
    size_t szScr   = (size_t)R * DCLS * 4;

    size_t needed = 4 * szPool + 2 * szX + szHead + 2 * szWh
                  + 4 * szXh + 2 * szW1t + szScr;

    bool mfma_ok = (ws_size >= needed) && (R % 128 == 0) && (CL % 128 == 0) && (K0 % 64 == 0);

    if (mfma_ok) {
        uint8_t* w = (uint8_t*)d_ws;
        size_t o = 0;
        _Float16* poolH   = (_Float16*)(w + o); o += szPool;
        _Float16* poolL   = (_Float16*)(w + o); o += szPool;
        _Float16* W0tH    = (_Float16*)(w + o); o += szPool;
        _Float16* W0tL    = (_Float16*)(w + o); o += szPool;
        float*    x0acc   = (float*)(w + o);    o += szX;
        float*    x1acc   = (float*)(w + o);    o += szX;
        float*    headacc = (float*)(w + o);    o += szHead;
        _Float16* WheadtH = (_Float16*)(w + o); o += szWh;
        _Float16* WheadtL = (_Float16*)(w + o); o += szWh;
        _Float16* x0H     = (_Float16*)(w + o); o += szXh;
        _Float16* x0L     = (_Float16*)(w + o); o += szXh;
        _Float16* x1H     = (_Float16*)(w + o); o += szXh;
        _Float16* x1L     = (_Float16*)(w + o); o += szXh;
        _Float16* W1tH    = (_Float16*)(w + o); o += szW1t;
        _Float16* W1tL    = (_Float16*)(w + o); o += szW1t;
        float*    scr     = (float*)(w + o);

        // decode/NMS arrays alias the pool region (dead after FC0)
        float* boxes = (float*)d_ws;
        float* bo    = boxes + (size_t)M * 4;
        float* area  = bo + (size_t)M * 4;
        float* smask = area + M;
        int*   cidx  = (int*)(smask + M);
        float* cscore = (float*)(cidx + (size_t)n * M);
        float* cbo   = cscore + (size_t)n * M;
        float* carea = cbo + (size_t)n * M * 4;

        // 0. zero accumulators + padded head weights (x0acc..WheadtL contiguous)
        {
            size_t zbytes = 2 * szX + szHead + 2 * szWh;   // 12 MB
            int c4 = (int)(zbytes / 16);
            zero_k<<<dim3((c4 + 255) / 256), dim3(256), 0, stream>>>((float4*)x0acc, c4);
        }
        // 1. weight converts
        convert_w_t_k<<<dim3(K0 / 64, CL / 64), dim3(256), 0, stream>>>(W0, W0tH, W0tL, K0, CL);
        convert_w_t_k<<<dim3(CL / 64, CL / 64), dim3(256), 0, stream>>>(W1, W1tH, W1tL, CL, CL);
        convert_w_t_guard_k<<<dim3(CL / 64, (NCLS + 63) / 64), dim3(256), 0, stream>>>(
            Wc, WheadtH, WheadtL, CL, NCLS, CL, 0);
        convert_w_t_guard_k<<<dim3(CL / 64, (NCLS * 4 + 63) / 64), dim3(256), 0, stream>>>(
            Wr, WheadtH, WheadtL, CL, NCLS * 4, CL, NCLS);
        // 2. RoI align -> f16 hi/lo pooled
        roi_align_f16v_k<<<dim3(R * 49), dim3(64), 0, stream>>>(
            prop, imidx, f0, f1, f2, f3, h0, h1, h2, h3, poolH, poolL);
        // 3. FC0: x0acc = pooled @ W0  (split-K 14, Kc=896)
        gemm_mfma_split_k<<<dim3(CL / 128, R / 128, 14), dim3(256), 0, stream>>>(
            poolH, poolL, W0tH, W0tL, x0acc, R, CL, K0, K0 / 14);
        // 4. x0 = relu(x0acc + b0) -> hi/lo
        act_split_k<<<dim3((R * CL / 4 + 255) / 256), dim3(256), 0, stream>>>(
            x0acc, b0, x0H, x0L, R * CL, CL);
        // 5. FC1: x1acc = x0 @ W1  (split-K 8, Kc=128)
        gemm_mfma_split_k<<<dim3(CL / 128, R / 128, 8), dim3(256), 0, stream>>>(
            x0H, x0L, W1tH, W1tL, x1acc, R, CL, CL, CL / 8);
        // 6. x1 = relu(x1acc + b1) -> hi/lo
        act_split_k<<<dim3((R * CL / 4 + 255) / 256), dim3(256), 0, stream>>>(
            x1acc, b1, x1H, x1L, R * CL, CL);
        // 7. combined heads: headacc = x1 @ [Wc|Wr]  (N=512 padded, split-K 8)
        gemm_mfma_split_k<<<dim3(NHEAD / 128, R / 128, 8), dim3(256), 0, stream>>>(
            x1H, x1L, WheadtH, WheadtL, headacc, R, NHEAD, CL, CL / 8);
        // 8. softmax (+bc) + decode (+br)
        softmax_k<<<dim3(R), dim3(64), 0, stream>>>(headacc, NHEAD, bc, scr);
        decode_k<<<dim3((M + 255) / 256), dim3(256), 0, stream>>>(
            prop, imidx, headacc, NHEAD, NCLS, br, scr, imsz, sthr, msz,
            boxes, bo, area, smask, M);
        // 9. NMS
        nms_k<<<dim3(n), dim3(NMS_T), 0, stream>>>(
            smask, bo, area, boxes, imidx, ithr,
            cidx, cscore, cbo, carea, outf, M, n, imtop);
    } else {
        // -------- fallback: R2 all-fp32 pipeline --------
        float* ws = (float*)d_ws;
        size_t off = 0;
        float* pooled  = ws + off; off += (size_t)R * K0;
        float* x0acc   = ws + off; off += (size_t)R * CL;
        float* x1acc   = ws + off; off += (size_t)R * CL;
        float* logits  = ws + off; off += (size_t)R * NCLS;
        off = (off + 3) & ~(size_t)3;
        float* reg     = ws + off; off += (size_t)R * NCLS * 4;
        float* scr     = ws + off; off += (size_t)R * DCLS;

        float* boxes = ws;
        float* bo    = boxes + (size_t)M * 4;
        float* area  = bo + (size_t)M * 4;
        float* smask = area + M;
        int*   cidx  = (int*)(smask + M);
        float* cscore = (float*)(cidx + (size_t)n * M);
        float* cbo   = cscore + (size_t)n * M;
        float* carea = cbo + (size_t)n * M * 4;

        {
            size_t zcount = (size_t)(reg + (size_t)R * NCLS * 4 - x0acc);
            int c4 = (int)(zcount / 4);
            zero_k<<<dim3((c4 + 255) / 256), dim3(256), 0, stream>>>((float4*)x0acc, c4);
        }
        roi_align_k<<<dim3(R * 49), dim3(256), 0, stream>>>(
            prop, imidx, f0, f1, f2, f3, h0, h1, h2, h3, pooled);
        gemm_splitk_k<<<dim3(CL / 64, R / 64, 8), dim3(256), 0, stream>>>(
            pooled, W0, nullptr, x0acc, R, CL, K0, 1568);
        gemm_splitk_k<<<dim3(CL / 64, R / 64, 4), dim3(256), 0, stream>>>(
            x0acc, W1, b0, x1acc, R, CL, CL, 256);
        gemm_splitk_k<<<dim3((NCLS + 63) / 64, R / 64, 8), dim3(256), 0, stream>>>(
            x1acc, Wc, b1, logits, R, NCLS, CL, 128);
        gemm_splitk_k<<<dim3((NCLS * 4 + 63) / 64, R / 64, 4), dim3(256), 0, stream>>>(
            x1acc, Wr, b1, reg, R, NCLS * 4, CL, 256);
        softmax_k<<<dim3(R), dim3(64), 0, stream>>>(logits, NCLS, bc, scr);
        decode_k<<<dim3((M + 255) / 256), dim3(256), 0, stream>>>(
            prop, imidx, reg, NCLS * 4, 0, br, scr, imsz, sthr, msz,
            boxes, bo, area, smask, M);
        nms_k<<<dim3(n), dim3(NMS_T), 0, stream>>>(
            smask, bo, area, boxes, imidx, ithr,
            cidx, cscore, cbo, carea, outf, M, n, imtop);
    }
}